// Round 7
// baseline (537.931 us; speedup 1.0000x reference)
//
#include <hip/hip_runtime.h>
#include <math.h>

#define NH    8
#define NQB   4
#define NPAIR 32
#define NTOK  1024
#define DH    64
#define DIMX  512
#define NROWS (NPAIR*NTOK)

typedef __attribute__((ext_vector_type(8))) short short8;
typedef _Float16 half8 __attribute__((ext_vector_type(8)));
typedef __attribute__((ext_vector_type(4))) float f32x4;

__device__ __forceinline__ unsigned short f2bf(float x){
  unsigned u = __float_as_uint(x);
  u += 0x7fffu + ((u>>16)&1u);
  return (unsigned short)(u>>16);
}
__device__ __forceinline__ float bf2f(unsigned short h){
  return __uint_as_float(((unsigned)h)<<16);
}
__device__ __forceinline__ unsigned short f2h(float x){
  union{ _Float16 f; unsigned short u; } c; c.f = (_Float16)x; return c.u;
}
__device__ __forceinline__ float h2f(unsigned short u){
  union{ _Float16 f; unsigned short u; } c; c.u = u; return (float)c.f;
}
__device__ __forceinline__ f32x4 mfma16(short8 a, short8 b, f32x4 c){
  return __builtin_amdgcn_mfma_f32_16x16x32_bf16(a,b,c,0,0,0);
}
__device__ __forceinline__ f32x4 mfma16f(half8 a, half8 b, f32x4 c){
  return __builtin_amdgcn_mfma_f32_16x16x32_f16(a,b,c,0,0,0);
}

// ------------------------------------------------- per-token LN statistics

__global__ __launch_bounds__(256) void k_lnstats(const float* __restrict__ q,
    const float* __restrict__ k, const float* __restrict__ v,
    float* __restrict__ mu_rstd){
  int wid = threadIdx.x >> 6, lane = threadIdx.x & 63;
  int tok = blockIdx.x*4 + wid;            // 0..12287
  const float* src = (tok < 4096) ? q : ((tok < 8192) ? k : v);
  int t = tok & 4095;
  const float4* p4 = (const float4*)(src + (size_t)t*DIMX) + lane*2;
  float4 a = p4[0], b = p4[1];
  float s  = a.x+a.y+a.z+a.w + b.x+b.y+b.z+b.w;
  float ss = a.x*a.x+a.y*a.y+a.z*a.z+a.w*a.w
           + b.x*b.x+b.y*b.y+b.z*b.z+b.w*b.w;
  #pragma unroll
  for (int off=32; off; off>>=1){ s += __shfl_down(s,off); ss += __shfl_down(ss,off); }
  if (lane==0){
    float mu = s*(1.0f/512.0f);
    float var = ss*(1.0f/512.0f) - mu*mu;
    mu_rstd[tok*2+0] = mu;
    mu_rstd[tok*2+1] = 1.0f/sqrtf(var + 1e-5f);
  }
}

// ---------------- transpose + hi/lo split of W_in and W_out -> [n][k] bf16

__global__ __launch_bounds__(256) void k_splitW(const float* __restrict__ Wa,
    const float* __restrict__ Wb,
    unsigned short* __restrict__ Wth, unsigned short* __restrict__ Wtl,
    unsigned short* __restrict__ Woth, unsigned short* __restrict__ Wotl){
  __shared__ float tile[64][65];
  int z = blockIdx.z;
  const float* W = z ? Wb : Wa;
  unsigned short* oh_ = z ? Woth : Wth;
  unsigned short* ol_ = z ? Wotl : Wtl;
  int kb = blockIdx.x, nb = blockIdx.y, tid = threadIdx.x;
  #pragma unroll
  for (int it=0; it<4; ++it){
    int idx = tid + 256*it;          // 0..1023
    int kr = idx>>4, c4 = idx&15;
    float4 vv = *(const float4*)(W + (size_t)(kb*64+kr)*DIMX + nb*64 + c4*4);
    tile[c4*4+0][kr]=vv.x; tile[c4*4+1][kr]=vv.y; tile[c4*4+2][kr]=vv.z; tile[c4*4+3][kr]=vv.w;
  }
  __syncthreads();
  #pragma unroll
  for (int it=0; it<4; ++it){
    int idx = tid + 256*it;
    int n = idx>>4, k4 = idx&15;
    size_t base = (size_t)(nb*64+n)*DIMX + kb*64 + k4*4;
    ushort4 hv, lv;
    { float xx=tile[n][k4*4+0]; unsigned short hh=f2bf(xx); hv.x=hh; lv.x=f2bf(xx-bf2f(hh)); }
    { float xx=tile[n][k4*4+1]; unsigned short hh=f2bf(xx); hv.y=hh; lv.y=f2bf(xx-bf2f(hh)); }
    { float xx=tile[n][k4*4+2]; unsigned short hh=f2bf(xx); hv.z=hh; lv.z=f2bf(xx-bf2f(hh)); }
    { float xx=tile[n][k4*4+3]; unsigned short hh=f2bf(xx); hv.w=hh; lv.w=f2bf(xx-bf2f(hh)); }
    *(ushort4*)(oh_+base) = hv;
    *(ushort4*)(ol_+base) = lv;
  }
}

// --------------- LN + projection GEMM via split-bf16 MFMA (q, k, v by z)

__global__ __launch_bounds__(256) void k_projmm(
    const float* __restrict__ q, const float* __restrict__ k, const float* __restrict__ v,
    const float* __restrict__ g, const float* __restrict__ bln,
    const unsigned short* __restrict__ Wth, const unsigned short* __restrict__ Wtl,
    const float* __restrict__ mu_rstd,
    unsigned short* __restrict__ fqh, unsigned short* __restrict__ fql,
    unsigned short* __restrict__ fkh, unsigned short* __restrict__ fkl,
    float* __restrict__ fv,
    double* __restrict__ qgs, double* __restrict__ kgs){
  __shared__ __align__(16) unsigned short Ahs[64*72];
  __shared__ __align__(16) unsigned short Als[64*72];
  __shared__ float scrc[4][128];
  int z = blockIdx.z;
  const float* x = (z==0) ? q : ((z==1) ? k : v);
  int mb = blockIdx.x, nb = blockIdx.y;
  int tid = threadIdx.x, w = tid>>6, l = tid&63, lm = l&15, qd = l>>4;
  int rbase = (w&1)*32;
  int cbase = nb*128 + (w>>1)*64;
  scrc[tid>>7][tid&127] = 0.f;
  scrc[2+(tid>>7)][tid&127] = 0.f;
  f32x4 acc[2][4];
  #pragma unroll
  for (int mt=0;mt<2;++mt)
    #pragma unroll
    for (int nt=0;nt<4;++nt) acc[mt][nt] = (f32x4){0.f,0.f,0.f,0.f};
  for (int kc8 = 0; kc8 < 8; ++kc8){
    float4 xv[4]; float mus[4], rss[4]; float4 gv[4], bv[4]; int rr[4], kk4[4];
    #pragma unroll
    for (int it=0; it<4; ++it){
      int idx = tid + 256*it;          // 0..1023
      int r = idx>>4, k4 = idx&15;
      rr[it]=r; kk4[it]=k4;
      int tokg = z*4096 + mb*64 + r;
      mus[it] = mu_rstd[tokg*2+0]; rss[it] = mu_rstd[tokg*2+1];
      xv[it] = *(const float4*)(x + (size_t)(mb*64+r)*DIMX + kc8*64 + k4*4);
      gv[it] = *(const float4*)(g   + kc8*64 + k4*4);
      bv[it] = *(const float4*)(bln + kc8*64 + k4*4);
    }
    __syncthreads();
    #pragma unroll
    for (int it=0; it<4; ++it){
      float y0 = (xv[it].x-mus[it])*rss[it]*gv[it].x + bv[it].x;
      float y1 = (xv[it].y-mus[it])*rss[it]*gv[it].y + bv[it].y;
      float y2 = (xv[it].z-mus[it])*rss[it]*gv[it].z + bv[it].z;
      float y3 = (xv[it].w-mus[it])*rss[it]*gv[it].w + bv[it].w;
      ushort4 hv, lv;
      { unsigned short hh=f2bf(y0); hv.x=hh; lv.x=f2bf(y0-bf2f(hh)); }
      { unsigned short hh=f2bf(y1); hv.y=hh; lv.y=f2bf(y1-bf2f(hh)); }
      { unsigned short hh=f2bf(y2); hv.z=hh; lv.z=f2bf(y2-bf2f(hh)); }
      { unsigned short hh=f2bf(y3); hv.w=hh; lv.w=f2bf(y3-bf2f(hh)); }
      *(ushort4*)(Ahs + rr[it]*72 + kk4[it]*4) = hv;
      *(ushort4*)(Als + rr[it]*72 + kk4[it]*4) = lv;
    }
    __syncthreads();
    #pragma unroll
    for (int kch=0; kch<2; ++kch){
      short8 a_h[2], a_l[2];
      #pragma unroll
      for (int mt=0;mt<2;++mt){
        a_h[mt] = *(const short8*)(Ahs + (rbase+mt*16+lm)*72 + kch*32 + qd*8);
        a_l[mt] = *(const short8*)(Als + (rbase+mt*16+lm)*72 + kch*32 + qd*8);
      }
      #pragma unroll
      for (int nt=0;nt<4;++nt){
        int cg = cbase + nt*16 + lm;
        size_t wix = (size_t)cg*DIMX + kc8*64 + kch*32 + qd*8;
        short8 bh = *(const short8*)(Wth + wix);
        short8 bl = *(const short8*)(Wtl + wix);
        #pragma unroll
        for (int mt=0;mt<2;++mt){
          acc[mt][nt] = mfma16(a_h[mt], bh, acc[mt][nt]);
          acc[mt][nt] = mfma16(a_h[mt], bl, acc[mt][nt]);
          acc[mt][nt] = mfma16(a_l[mt], bh, acc[mt][nt]);
        }
      }
    }
  }
  int head = cbase >> 6;
  if (z < 2){
    unsigned short* hd = (z==0) ? fqh : fkh;
    unsigned short* ld_ = (z==0) ? fql : fkl;
    float csum[4] = {0.f,0.f,0.f,0.f};
    #pragma unroll
    for (int mt=0;mt<2;++mt){
      #pragma unroll
      for (int nt=0;nt<4;++nt){
        #pragma unroll
        for (int i=0;i<4;++i){
          float val = acc[mt][nt][i];
          csum[nt] += val;
          int tglob = mb*64 + rbase + mt*16 + qd*4 + i;
          int qb = tglob>>10, n = tglob&1023;
          int p = head*4 + qb;
          int d = nt*16 + lm;
          size_t ix = ((size_t)(p*NTOK+n))*DH + d;
          unsigned short hh = f2bf(val);
          hd[ix] = hh; ld_[ix] = f2bf(val - bf2f(hh));
        }
      }
    }
    #pragma unroll
    for (int m=16;m<64;m<<=1){
      #pragma unroll
      for (int nt=0;nt<4;++nt) csum[nt] += __shfl_xor(csum[nt], m);
    }
    if (qd==0){
      #pragma unroll
      for (int nt=0;nt<4;++nt) scrc[w][(w>>1)*64 + nt*16 + lm] = csum[nt];
    }
    __syncthreads();
    if (tid < 128){
      float s = scrc[0][tid]+scrc[1][tid]+scrc[2][tid]+scrc[3][tid];
      double* dst = (z==0) ? qgs : kgs;
      atomicAdd(&dst[nb*128 + tid], (double)s);
    }
  } else {
    #pragma unroll
    for (int mt=0;mt<2;++mt){
      #pragma unroll
      for (int nt=0;nt<4;++nt){
        #pragma unroll
        for (int i=0;i<4;++i){
          int tglob = mb*64 + rbase + mt*16 + qd*4 + i;
          int qb = tglob>>10, n = tglob&1023;
          int p = head*4 + qb;
          int d = nt*16 + lm;
          fv[((size_t)(p*NTOK+n))*DH + d] = acc[mt][nt][i];
        }
      }
    }
  }
}

// ------------------------ transpose fv -> fvT (fp16 hi/lo, [p][d][m])

__global__ __launch_bounds__(256) void k_vT(const float* __restrict__ fv,
    unsigned short* __restrict__ fvTh, unsigned short* __restrict__ fvTl){
  __shared__ float tile[64][65];
  int mc = blockIdx.x, p = blockIdx.y, tid = threadIdx.x;
  #pragma unroll
  for (int it=0; it<4; ++it){
    int idx = tid + 256*it;
    int m = idx>>4, d4 = idx&15;
    float4 vv = *(const float4*)(fv + ((size_t)(p*NTOK + mc*64 + m)*DH + d4*4));
    tile[d4*4+0][m]=vv.x; tile[d4*4+1][m]=vv.y; tile[d4*4+2][m]=vv.z; tile[d4*4+3][m]=vv.w;
  }
  __syncthreads();
  #pragma unroll
  for (int it=0; it<2; ++it){
    int idx = tid + 256*it;       // 0..511
    int d = idx>>3, seg = idx&7;  // 8 m per thread
    size_t base = (size_t)(p*DH + d)*NTOK + mc*64 + seg*8;
    ushort4 h0,h1,l0,l1;
    { float xx=tile[d][seg*8+0]; unsigned short hh=f2h(xx); h0.x=hh; l0.x=f2h(xx-h2f(hh)); }
    { float xx=tile[d][seg*8+1]; unsigned short hh=f2h(xx); h0.y=hh; l0.y=f2h(xx-h2f(hh)); }
    { float xx=tile[d][seg*8+2]; unsigned short hh=f2h(xx); h0.z=hh; l0.z=f2h(xx-h2f(hh)); }
    { float xx=tile[d][seg*8+3]; unsigned short hh=f2h(xx); h0.w=hh; l0.w=f2h(xx-h2f(hh)); }
    { float xx=tile[d][seg*8+4]; unsigned short hh=f2h(xx); h1.x=hh; l1.x=f2h(xx-h2f(hh)); }
    { float xx=tile[d][seg*8+5]; unsigned short hh=f2h(xx); h1.y=hh; l1.y=f2h(xx-h2f(hh)); }
    { float xx=tile[d][seg*8+6]; unsigned short hh=f2h(xx); h1.z=hh; l1.z=f2h(xx-h2f(hh)); }
    { float xx=tile[d][seg*8+7]; unsigned short hh=f2h(xx); h1.w=hh; l1.w=f2h(xx-h2f(hh)); }
    *(ushort4*)(fvTh+base)   = h0;
    *(ushort4*)(fvTh+base+4) = h1;
    *(ushort4*)(fvTl+base)   = l0;
    *(ushort4*)(fvTl+base+4) = l1;
  }
}

// -------------------------------------------- nu (col-means of f_k) and S

__global__ __launch_bounds__(256) void k_nu(const unsigned short* __restrict__ fkh,
    const unsigned short* __restrict__ fkl,
    float* __restrict__ nuA, float* __restrict__ Sarr){
  __shared__ float red[4][64];
  int p = blockIdx.x, tid = threadIdx.x;
  int td = tid & 63, tm = tid >> 6;
  float s = 0.f;
  for (int m = tm; m < NTOK; m += 4){
    size_t ix = (size_t)(p*NTOK+m)*DH + td;
    s += bf2f(fkh[ix]) + bf2f(fkl[ix]);
  }
  red[tm][td] = s;
  __syncthreads();
  if (tid < 64){
    float tot = red[0][tid]+red[1][tid]+red[2][tid]+red[3][tid];
    float nuv = tot * (1.0f/1024.0f);
    nuA[p*DH+tid] = nuv;
    float sv = nuv;
    #pragma unroll
    for (int off=32; off; off>>=1) sv += __shfl_down(sv, off);
    if (tid==0) Sarr[p] = sv;
  }
}

// --------------------------------------- per-row scalars for f_q and f_k

__global__ __launch_bounds__(256) void k_rows(
    const unsigned short* __restrict__ fqh, const unsigned short* __restrict__ fql,
    const unsigned short* __restrict__ fkh, const unsigned short* __restrict__ fkl,
    const float* __restrict__ nuA,
    float* __restrict__ inv_na_q, float* __restrict__ muqA, float* __restrict__ tqA,
    float* __restrict__ inv_na_k, float* __restrict__ skA){
  int wid = threadIdx.x >> 6, lane = threadIdx.x & 63;
  int row = blockIdx.x*4 + wid;            // < 32768
  int p = row >> 10;
  size_t ix = (size_t)row*DH + lane;
  float xq = bf2f(fqh[ix]) + bf2f(fql[ix]);
  float nv = nuA[p*DH + lane];
  float s = xq, ss = xq*xq, sd = xq*nv;
  #pragma unroll
  for (int off=32; off; off>>=1){
    s += __shfl_down(s,off); ss += __shfl_down(ss,off); sd += __shfl_down(sd,off);
  }
  if (lane==0){
    float nrm = sqrtf(ss);
    inv_na_q[row] = 1.0f/(nrm+1e-8f);
    muqA[row] = s*(1.0f/64.0f);
    tqA[row] = sd;
  }
  float xk = bf2f(fkh[ix]) + bf2f(fkl[ix]);
  float s2 = xk, ss2 = xk*xk;
  #pragma unroll
  for (int off=32; off; off>>=1){
    s2 += __shfl_down(s2,off); ss2 += __shfl_down(ss2,off);
  }
  if (lane==0){
    float nrm = sqrtf(ss2);
    inv_na_k[row] = 1.0f/(nrm+1e-8f);
    skA[row] = s2;
  }
}

// ------------------------------------------------- weight predictor (tiny)

__global__ __launch_bounds__(256) void k_wp(const double* __restrict__ qgs,
    const double* __restrict__ kgs,
    const float* __restrict__ W1, const float* __restrict__ b1,
    const float* __restrict__ lgv, const float* __restrict__ lbv,
    const float* __restrict__ W2, const float* __restrict__ b2,
    const float* __restrict__ W3, const float* __restrict__ b3,
    const float* __restrict__ wtemp, float* __restrict__ wp_out){
  __shared__ float feats[8][128];
  __shared__ float h1[8][64];
  __shared__ float h2s[8][32];
  __shared__ float lgt[8][3];
  __shared__ float mv[8][2];
  int tid = threadIdx.x;
  for (int idx = tid; idx < 1024; idx += 256){
    int h = idx >> 7, i = idx & 127;
    double vv = (i < 64) ? qgs[h*64+i] : kgs[h*64+(i-64)];
    feats[h][i] = (float)(vv * (1.0/4096.0));
  }
  __syncthreads();
  for (int idx = tid; idx < 512; idx += 256){
    int h = idx >> 6, j = idx & 63;
    float s = b1[j];
    for (int i = 0; i < 128; ++i) s += feats[h][i]*W1[i*64+j];
    h1[h][j] = s;
  }
  __syncthreads();
  if (tid < 8){
    float s=0.f, ss=0.f;
    for (int j=0;j<64;++j){ float vv=h1[tid][j]; s+=vv; ss+=vv*vv; }
    float mu = s*(1.0f/64.0f);
    float var = ss*(1.0f/64.0f)-mu*mu;
    mv[tid][0]=mu; mv[tid][1]=1.0f/sqrtf(var+1e-5f);
  }
  __syncthreads();
  for (int idx = tid; idx < 512; idx += 256){
    int h = idx>>6, j = idx&63;
    float vv = (h1[h][j]-mv[h][0])*mv[h][1]*lgv[j] + lbv[j];
    h1[h][j] = fmaxf(vv, 0.f);
  }
  __syncthreads();
  {
    int h = tid >> 5, j = tid & 31;
    float s = b2[j];
    for (int i=0;i<64;++i) s += h1[h][i]*W2[i*32+j];
    h2s[h][j] = fmaxf(s, 0.f);
  }
  __syncthreads();
  if (tid < 24){
    int h = tid/3, j = tid - h*3;
    float s = b3[j];
    for (int i=0;i<32;++i) s += h2s[h][i]*W3[i*3+j];
    lgt[h][j] = s;
  }
  __syncthreads();
  if (tid < 8){
    int h = tid;
    float z0=lgt[h][0], z1=lgt[h][1], z2=lgt[h][2];
    float m = fmaxf(z0,fmaxf(z1,z2));
    float e0=expf(z0-m), e1=expf(z1-m), e2=expf(z2-m);
    float inv = 1.0f/(e0+e1+e2);
    float l0=e0*inv, l1=e1*inv, l2=e2*inv;
    float wt = fminf(fmaxf(wtemp[0], 0.1f), 20.0f);
    float y0=l0/wt, y1=l1/wt, y2=l2/wt;
    float m2 = fmaxf(y0,fmaxf(y1,y2));
    float f0=expf(y0-m2), f1=expf(y1-m2), f2=expf(y2-m2);
    float inv2 = 1.0f/(f0+f1+f2);
    float w0=f0*inv2, w1=f1*inv2, w2=f2*inv2;
    w0 = fminf(fmaxf(w0,0.05f),0.8f);
    w1 = fminf(fmaxf(w1,0.05f),0.8f);
    w2 = fminf(fmaxf(w2,0.05f),0.8f);
    float isum = 1.0f/(w0+w1+w2);
    wp_out[h*3+0]=w0*isum; wp_out[h*3+1]=w1*isum; wp_out[h*3+2]=w2*isum;
  }
}

// ------------- pass A (MFMA): QK^T, derive cos/cov/margin, stats
// grid 2048: block = 32 rows x 512 keys (ksl), wave = 16 rows x 256 keys.
// Fully unrolled 4-chunk body, no in-loop barriers; per-(row,ksl) partials.

__global__ __launch_bounds__(256) void k_passA(
    const unsigned short* __restrict__ fqh, const unsigned short* __restrict__ fql,
    const unsigned short* __restrict__ fkh, const unsigned short* __restrict__ fkl,
    const float* __restrict__ inv_na_q, const float* __restrict__ muqA,
    const float* __restrict__ tqA,
    const float* __restrict__ inv_na_k, const float* __restrict__ skA,
    const float* __restrict__ Sarr,
    float* __restrict__ rsPcos, float* __restrict__ rsPcov, float* __restrict__ rsPmarg,
    float* __restrict__ mxP, float* __restrict__ mnP,
    float* __restrict__ xvP, float* __restrict__ nvP,
    double* __restrict__ gacc){
  __shared__ float redbuf[4][16][7];
  __shared__ double wredS[4][3];
  int b = blockIdx.x;
  int p = ((b&7)<<2) | ((b>>3)&3);   // XCD swizzle
  int s = b>>5;                      // 0..63
  int rg = s & 31, ksl = s >> 5;
  int n0 = rg*32;
  int tid = threadIdx.x, w = tid>>6, l = tid&63;
  int lm = l&15, q = l>>4;
  int rh = w&1, ks2 = w>>1;
  int nw = n0 + rh*16;
  int kb0 = ksl*512 + ks2*256;
  float Sp = Sarr[p];
  const float inv8 = (float)(1.0/(8.0+1e-6));
  float ia[4], m8[4], t8[4];
  #pragma unroll
  for (int i=0;i<4;++i){
    int rgx = p*NTOK + nw + q*4 + i;
    float mq = muqA[rgx];
    ia[i] = inv_na_q[rgx];
    m8[i] = mq*inv8;
    t8[i] = (tqA[rgx] - mq*Sp)*inv8;
  }
  const short8* aqh = (const short8*)(fqh + (size_t)(p*NTOK + nw + lm)*DH);
  const short8* aql = (const short8*)(fql + (size_t)(p*NTOK + nw + lm)*DH);
  short8 ah0 = aqh[q], ah1 = aqh[4+q], al0 = aql[q], al1 = aql[4+q];
  const unsigned short* fkb_h = fkh + (size_t)p*NTOK*DH;
  const unsigned short* fkb_l = fkl + (size_t)p*NTOK*DH;
  const float* cAg = inv_na_k + p*NTOK;
  const float* cSg = skA + p*NTOK;
  float sc2=0.f, sv2=0.f, scv=0.f;
  float pc[4]={0,0,0,0}, pv_[4]={0,0,0,0}, pm[4]={0,0,0,0};
  float xc[4], nc[4], xv[4], nv[4];
  #pragma unroll
  for (int i=0;i<4;++i){ xc[i]=-1e30f; nc[i]=1e30f; xv[i]=-1e30f; nv[i]=1e30f; }
  #pragma unroll
  for (int c8=0; c8<4; ++c8){
    int m0 = kb0 + c8*64;
    float caA[4], csA[4];
    #pragma unroll
    for (int ct=0; ct<4; ++ct){
      caA[ct] = cAg[m0+ct*16+lm];
      csA[ct] = cSg[m0+ct*16+lm];
    }
    f32x4 acc[4];
    #pragma unroll
    for (int ct=0; ct<4; ++ct){
      const short8* bh = (const short8*)(fkb_h + (size_t)(m0+ct*16+lm)*DH);
      const short8* bl = (const short8*)(fkb_l + (size_t)(m0+ct*16+lm)*DH);
      short8 kh0=bh[q], kh1=bh[4+q], kl0=bl[q], kl1=bl[4+q];
      f32x4 a2 = {0.f,0.f,0.f,0.f};
      a2 = mfma16(ah0,kh0,a2); a2 = mfma16(ah1,kh1,a2);
      a2 = mfma16(al0,kh0,a2); a2 = mfma16(al1,kh1,a2);
      a2 = mfma16(ah0,kl0,a2); a2 = mfma16(ah1,kl1,a2);
      acc[ct] = a2;
    }
    #pragma unroll
    for (int ct=0; ct<4; ++ct){
      float ca = caA[ct], cs = csA[ct];
      #pragma unroll
      for (int i=0;i<4;++i){
        float dot = acc[ct][i];
        float cosv = fminf(fmaxf(dot*ia[i]*ca,-0.99f),0.99f);
        float cov  = fmaf(-m8[i], cs, fmaf(dot, inv8, -t8[i]));
        float marg = fmaxf(0.01f - cosv, 0.f);
        sc2 = fmaf(cosv,cosv,sc2); sv2 = fmaf(cov,cov,sv2); scv = fmaf(cosv,cov,scv);
        pc[i]+=cosv; pv_[i]+=cov; pm[i]+=marg;
        xc[i]=fmaxf(xc[i],cosv); nc[i]=fminf(nc[i],cosv);
        xv[i]=fmaxf(xv[i],cov);  nv[i]=fminf(nv[i],cov);
      }
    }
  }
  #pragma unroll
  for (int m=1;m<16;m<<=1){
    #pragma unroll
    for (int i=0;i<4;++i){
      pc[i]+=__shfl_xor(pc[i],m); pv_[i]+=__shfl_xor(pv_[i],m); pm[i]+=__shfl_xor(pm[i],m);
      xc[i]=fmaxf(xc[i],__shfl_xor(xc[i],m)); nc[i]=fminf(nc[i],__shfl_xor(nc[i],m));
      xv[i]=fmaxf(xv[i],__shfl_xor(xv[i],m)); nv[i]=fminf(nv[i],__shfl_xor(nv[i],m));
    }
  }
  if (lm==0){
    #pragma unroll
    for (int i=0;i<4;++i){
      int r16 = q*4+i;
      redbuf[w][r16][0]=pc[i]; redbuf[w][r16][1]=pv_[i]; redbuf[w][r16][2]=pm[i];
      redbuf[w][r16][3]=xc[i]; redbuf[w][r16][4]=nc[i];
      redbuf[w][r16][5]=xv[i]; redbuf[w][r16][6]=nv[i];
    }
  }
  double vals[3] = {(double)sc2,(double)sv2,(double)scv};
  #pragma unroll
  for (int c2=0;c2<3;++c2){
    double vv = vals[c2];
    #pragma unroll
    for (int off=32; off; off>>=1) vv += __shfl_down(vv, off);
    if (l==0) wredS[w][c2] = vv;
  }
  __syncthreads();
  if (tid < 32){
    int rh2 = tid>>4, r16 = tid&15;
    int w0 = rh2, w1 = rh2+2;          // two ks2 waves of this row half
    float sc = redbuf[w0][r16][0]+redbuf[w1][r16][0];
    float sv = redbuf[w0][r16][1]+redbuf[w1][r16][1];
    float sm = redbuf[w0][r16][2]+redbuf[w1][r16][2];
    float mxc = fmaxf(redbuf[w0][r16][3],redbuf[w1][r16][3]);
    float mnc = fminf(redbuf[w0][r16][4],redbuf[w1][r16][4]);
    float mxv = fmaxf(redbuf[w0][r16][5],redbuf[w1][r16][5]);
    float mnv = fminf(redbuf[w0][r16][6],redbuf[w1][r16][6]);
    int row = p*NTOK + n0 + tid;
    int i2 = row*2 + ksl;
    rsPcos[i2]=sc; rsPcov[i2]=sv; rsPmarg[i2]=sm;
    mxP[i2]=mxc; mnP[i2]=mnc; xvP[i2]=mxv; nvP[i2]=mnv;
  }
  if (tid == 0){
    int h = p >> 2;
    #pragma unroll
    for (int c2=0;c2<3;++c2){
      double t = wredS[0][c2]+wredS[1][c2]+wredS[2][c2]+wredS[3][c2];
      atomicAdd(&gacc[h*3+c2], t);
    }
  }
}

// ---------------------- row finish: combine ksl partials, var_row, moments

__global__ __launch_bounds__(256) void k_rowfin(
    const float* __restrict__ rsPcos, const float* __restrict__ rsPcov,
    const float* __restrict__ rsPmarg,
    const float* __restrict__ mxP, const float* __restrict__ mnP,
    const float* __restrict__ xvP, const float* __restrict__ nvP,
    float* __restrict__ var_row,
    float* __restrict__ mxcos, float* __restrict__ mncos,
    float* __restrict__ mxcov, float* __restrict__ mncov,
    double* __restrict__ racc){
  __shared__ double wredS[4][6];
  int row = blockIdx.x*256 + threadIdx.x;
  int p = row >> 10; int h = p >> 2;
  float sc = rsPcos[row*2] + rsPcos[row*2+1];
  float sv = rsPcov[row*2] + rsPcov[row*2+1];
  float sm = rsPmarg[row*2] + rsPmarg[row*2+1];
  mxcos[row] = fmaxf(mxP[row*2], mxP[row*2+1]);
  mncos[row] = fminf(mnP[row*2], mnP[row*2+1]);
  mxcov[row] = fmaxf(xvP[row*2], xvP[row*2+1]);
  mncov[row] = fminf(nvP[row*2], nvP[row*2+1]);
  float vr = sm * (1.0f/1024.0f);
  var_row[row] = vr;
  double dv = (double)vr;
  double rc = (double)sc, rv = (double)sv;
  double vals[6];
  vals[0] = 1024.0*dv;
  vals[1] = 1024.0*dv*dv;
  vals[2] = dv*rc;
  vals[3] = dv*rv;
  vals[4] = rc;
  vals[5] = rv;
  int lane = threadIdx.x & 63, wid = threadIdx.x >> 6;
  #pragma unroll
  for (int c2 = 0; c2 < 6; ++c2){
    double vv = vals[c2];
    #pragma unroll
    for (int off=32; off; off>>=1) vv += __shfl_down(vv, off);
    if (lane==0) wredS[wid][c2] = vv;
  }
  __syncthreads();
  if (threadIdx.x == 0){
    #pragma unroll
    for (int c2 = 0; c2 < 6; ++c2){
      double t = wredS[0][c2]+wredS[1][c2]+wredS[2][c2]+wredS[3][c2];
      atomicAdd(&racc[h*6+c2], t);
    }
  }
}

// ------------------------------------- finalize scalars -> d2 coefficients
// gacc[h*3+{0,1,2}] = {Sum cos^2, Sum cov^2, Sum cos*cov}
// racc[h*6+{0..5}]  = {Sum var, Sum var^2, Sum var*cos, Sum var*cov, Sum cos, Sum cov}

__global__ void k_final(const double* __restrict__ gacc, const double* __restrict__ racc,
                        const float* __restrict__ wp_out, float* __restrict__ coef){
  if (threadIdx.x != 0) return;
  const double N = 33554432.0;
  double Sc1=0,Sc2=0,Sv1=0,Sv2=0,Sr1=0,Sr2=0;
  for (int h=0;h<8;++h){
    Sc2+=gacc[h*3+0]; Sv2+=gacc[h*3+1];
    Sr1+=racc[h*6+0]; Sr2+=racc[h*6+1];
    Sc1+=racc[h*6+4]; Sv1+=racc[h*6+5];
  }
  double cvar = (Sc2 - Sc1*Sc1/N)/(N-1.0);
  double cn = sqrt(fmax(cvar,0.0)) + 1e-6;
  double cscale = (cn < 1e-4) ? 0.1 : 1.0;
  double vraw = (Sv2 - Sv1*Sv1/N)/(N-1.0);
  double sraw = sqrt(fmax(vraw,0.0));
  double basev = 0.001/1024.0;
  double regv = (sraw < 1e-6) ? basev*10.0 : basev;
  double covn = regv*sraw + 1e-6;
  double vvar = (Sr2 - Sr1*Sr1/N)/(N-1.0);
  double vn = sqrt(fmax(vvar,0.0)) + 1e-6;
  double ah[8], bh[8], chh[8];
  double Sd1=0.0, Sd2=0.0;
  for (int h=0;h<8;++h){
    double a = (double)wp_out[h*3+0]/cn*cscale;
    double b = (double)wp_out[h*3+1]*regv*0.5/covn;
    double c = (double)wp_out[h*3+2]*0.5/vn;
    ah[h]=a; bh[h]=b; chh[h]=c;
    Sd1 += a*racc[h*6+4] + b*racc[h*6+5] + c*racc[h*6+0];
    Sd2 += a*a*gacc[h*3+0] + b*b*gacc[h*3+1] + c*c*racc[h*6+1]
         + 2.0*(a*b*gacc[h*3+2] + a*c*racc[h*6+2] + b*c*racc[h*6+3]);
  }
  double dvar = (Sd2 - Sd1*Sd1/N)/(N-1.0);
  double dstd = sqrt(fmax(dvar,0.0));
  double temp = (dstd < 1e-6) ? 0.1 : 0.3 + dstd;
  double tcl = fmin(fmax(temp,0.1),5.0);
  double it = 1.0/tcl;
  for (int h=0;h<8;++h){
    coef[h*3+0] = (float)(ah[h]*it);
    coef[h*3+1] = (float)(bh[h]*it);
    coef[h*3+2] = (float)(chh[h]*it);
  }
}

// -------------------- pass C (MFMA): QK -> exp -> PV.
// grid 2048: block = 32 rows x 512 keys, wave = 16 rows x 256 keys, fully
// unrolled; per-wave private LDS P tile (no in-loop barriers); ks2 pair
// combined in LDS at block end (one barrier); pO[row][ksl][64] partials.

__global__ __launch_bounds__(256) void k_pv(
    const unsigned short* __restrict__ fqh, const unsigned short* __restrict__ fql,
    const unsigned short* __restrict__ fkh, const unsigned short* __restrict__ fkl,
    const unsigned short* __restrict__ fvTh, const unsigned short* __restrict__ fvTl,
    const float* __restrict__ inv_na_q, const float* __restrict__ muqA,
    const float* __restrict__ tqA,
    const float* __restrict__ inv_na_k, const float* __restrict__ skA,
    const float* __restrict__ Sarr, const float* __restrict__ var_row,
    const float* __restrict__ mxcosA, const float* __restrict__ mncosA,
    const float* __restrict__ mxcovA, const float* __restrict__ mncovA,
    const float* __restrict__ coef,
    float* __restrict__ pO, float* __restrict__ pden){
  __shared__ __align__(16) unsigned short ph[4][16][72];   // per-wave P tile (fp16)
  __shared__ float oc[2][16][68];
  __shared__ float dc[2][16];
  int b = blockIdx.x;
  int p = ((b&7)<<2) | ((b>>3)&3);   // XCD swizzle
  int s = b>>5;                      // 0..63
  int rg = s & 31, ksl = s >> 5;
  int n0 = rg*32;
  int h = p>>2;
  int tid = threadIdx.x, w = tid>>6, l = tid&63;
  int lm = l&15, q = l>>4;
  int rh = w&1, ks2 = w>>1;
  int nw = n0 + rh*16;
  int kb0 = ksl*512 + ks2*256;
  float A = coef[h*3+0], B = coef[h*3+1], C = coef[h*3+2];
  float Sp = Sarr[p];
  const float inv8 = (float)(1.0/(8.0+1e-6));
  float B8 = B*inv8;
  float ia[4], bm[4], o2[4];
  #pragma unroll
  for (int i=0;i<4;++i){
    int rgx = p*NTOK + nw + q*4 + i;
    float mq = muqA[rgx];
    ia[i] = inv_na_q[rgx];
    bm[i] = B8*mq;
    float tq2 = tqA[rgx] - mq*Sp;
    float vr = var_row[rgx];
    float Mh = fmaxf(A*mxcosA[rgx],A*mncosA[rgx]) + fmaxf(B*mxcovA[rgx],B*mncovA[rgx]) + C*vr;
    o2[i] = (C*vr - Mh) - B8*tq2;
  }
  const short8* aqh = (const short8*)(fqh + (size_t)(p*NTOK + nw + lm)*DH);
  const short8* aql = (const short8*)(fql + (size_t)(p*NTOK + nw + lm)*DH);
  short8 ah0 = aqh[q], ah1 = aqh[4+q], al0 = aql[q], al1 = aql[4+q];
  const unsigned short* fkb_h = fkh + (size_t)p*NTOK*DH;
  const unsigned short* fkb_l = fkl + (size_t)p*NTOK*DH;
  const float* cAg = inv_na_k + p*NTOK;
  const float* cSg = skA + p*NTOK;
  unsigned short* phW = &ph[w][0][0];
  f32x4 o[4];
  #pragma unroll
  for (int t=0;t<4;++t) o[t] = (f32x4){0.f,0.f,0.f,0.f};
  float den[4] = {0.f,0.f,0.f,0.f};
  #pragma unroll
  for (int c8=0; c8<4; ++c8){
    int m0 = kb0 + c8*64;
    float caA[4], csA[4];
    #pragma unroll
    for (int ct=0; ct<4; ++ct){
      caA[ct] = cAg[m0+ct*16+lm];
      csA[ct] = cSg[m0+ct*16+lm];
    }
    f32x4 acc[4];
    #pragma unroll
    for (int ct=0; ct<4; ++ct){
      const short8* bh = (const short8*)(fkb_h + (size_t)(m0+ct*16+lm)*DH);
      const short8* bl = (const short8*)(fkb_l + (size_t)(m0+ct*16+lm)*DH);
      short8 kh0=bh[q], kh1=bh[4+q], kl0=bl[q], kl1=bl[4+q];
      f32x4 a2 = {0.f,0.f,0.f,0.f};
      a2 = mfma16(ah0,kh0,a2); a2 = mfma16(ah1,kh1,a2);
      a2 = mfma16(al0,kh0,a2); a2 = mfma16(al1,kh1,a2);
      a2 = mfma16(ah0,kl0,a2); a2 = mfma16(ah1,kl1,a2);
      acc[ct] = a2;
    }
    #pragma unroll
    for (int ct=0; ct<4; ++ct){
      float ca = caA[ct], cs = csA[ct];
      #pragma unroll
      for (int i=0;i<4;++i){
        float dot = acc[ct][i];
        float cosv = fminf(fmaxf(dot*ia[i]*ca,-0.99f),0.99f);
        float arg = fmaf(A, cosv, fmaf(-bm[i], cs, fmaf(B8, dot, o2[i])));
        float e = __expf(arg);
        unsigned short us = f2h(e);
        phW[(q*4+i)*72 + ct*16+lm] = us;
        den[i] += h2f(us);
      }
    }
    #pragma unroll
    for (int t=0;t<4;++t){
      const half8* avh = (const half8*)(fvTh + (size_t)(p*DH + t*16 + lm)*NTOK + m0);
      const half8* avl = (const half8*)(fvTl + (size_t)(p*DH + t*16 + lm)*NTOK + m0);
      half8 vh0 = avh[q], vh1 = avh[4+q], vl0 = avl[q], vl1 = avl[4+q];
      half8 pb0 = *(const half8*)(phW + lm*72 + q*8);
      half8 pb1 = *(const half8*)(phW + lm*72 + 32 + q*8);
      o[t] = mfma16f(vh0, pb0, o[t]);
      o[t] = mfma16f(vl0, pb0, o[t]);
      o[t] = mfma16f(vh1, pb1, o[t]);
      o[t] = mfma16f(vl1, pb1, o[t]);
    }
  }
  #pragma unroll
  for (int m=1;m<16;m<<=1){
    #pragma unroll
    for (int i=0;i<4;++i) den[i] += __shfl_xor(den[i],m);
  }
  // combine the two key-half waves (ks2) of each row half
  if (ks2==1){
    #pragma unroll
    for (int t=0;t<4;++t)
      #pragma unroll
      for (int i=0;i<4;++i)
        oc[rh][lm][t*16+q*4+i] = o[t][i];
    if (lm==0){
      #pragma unroll
      for (int i=0;i<4;++i) dc[rh][q*4+i] = den[i];
    }
  }
  __syncthreads();
  if (ks2==0){
    #pragma unroll
    for (int t=0;t<4;++t)
      #pragma unroll
      for (int i=0;i<4;++i)
        o[t][i] += oc[rh][lm][t*16+q*4+i];
    if (lm==0){
      #pragma unroll
      for (int i=0;i<4;++i){
        int rowg = p*NTOK + nw + q*4 + i;
        pden[rowg*2 + ksl] = den[i] + dc[rh][q*4+i];
      }
    }
    size_t base = ((size_t)(p*NTOK + nw + lm)*2 + ksl)*DH;
    #pragma unroll
    for (int t=0;t<4;++t){
      *(float4*)(pO + base + t*16 + q*4) =
          make_float4(o[t][0], o[t][1], o[t][2], o[t][3]);
    }
  }
}

// ------------- combine K-split partials: O = sum(pO)/sum(pden) -> bf16 hi/lo

__global__ __launch_bounds__(256) void k_pvred(const float* __restrict__ pO,
    const float* __restrict__ pden,
    unsigned short* __restrict__ ohh, unsigned short* __restrict__ ohl){
  int idx = blockIdx.x*256 + threadIdx.x;   // 0..2M-1
  int row = idx >> 6, d = idx & 63;
  float num = pO[((size_t)row*2+0)*DH + d] + pO[((size_t)row*2+1)*DH + d];
  float dd  = pden[row*2+0] + pden[row*2+1];
  float val = num / dd;
  int p = row >> 10, n = row & 1023;
  int h = p >> 2, qb = p & 3;
  size_t oix = ((size_t)(qb*NTOK + n)*NH + h)*DH + d;
  unsigned short hh = f2bf(val);
  ohh[oix] = hh;
  ohl[oix] = f2bf(val - bf2f(hh));
}

// ----------------- output GEMM (MFMA, no LDS): oh @ W_out + b -> out

__global__ __launch_bounds__(256) void k_outmm(
    const unsigned short* __restrict__ ohh, const unsigned short* __restrict__ ohl,
    const unsigned short* __restrict__ Woth, const unsigned short* __restrict__ Wotl,
    const float* __restrict__ bias, float* __restrict__ out){
  int mb = blockIdx.x, nb = blockIdx.y;
  int tid = threadIdx.x, w = tid>>6, l = tid&63, lm = l&15, qd = l>>4;
  int rbase = mb*64 + (w&1)*32;
  int cbase = nb*128 + (w>>1)*64;
  f32x4 acc[2][4];
  #pragma unroll
  for (int mt=0;mt<2;++mt)
    #pragma unroll
    for (int nt=0;nt<4;++nt) acc[mt][nt] = (f32x4){0.f,0.f,0.f,0.f};
  for (int kc=0; kc<16; ++kc){
    short8 a_h[2], a_l[2];
    #pragma unroll
    for (int mt=0;mt<2;++mt){
      size_t aix = (size_t)(rbase+mt*16+lm)*DIMX + kc*32 + qd*8;
      a_h[mt] = *(const short8*)(ohh + aix);
      a_l[mt] = *(const short8*)(ohl + aix);
    }
    #pragma unroll
    for (int nt=0;nt<4;++nt){
      size_t wix = (size_t)(cbase+nt*16+lm)*DIMX + kc*32 + qd*8;
      short8 bh = *(const short8*)(Woth + wix);
      short8 bl = *(const short8*)(Wotl + wix);
      #pragma unroll
      for (int mt=0;mt<2;++mt){
        acc[mt][nt] = mfma16(a_h[mt], bh, acc[mt][nt]);
        acc[mt][nt] = mfma16(a_h[mt], bl, acc[mt][nt]);
        acc[mt][nt] = mfma16(a_l[mt], bh, acc[mt][nt]);
      }
    }
  }
  float bv[4];
  #pragma unroll
  for (int nt=0;nt<4;++nt) bv[nt] = bias[cbase+nt*16+lm];
  #pragma unroll
  for (int mt=0;mt<2;++mt){
    #pragma unroll
    for (int i=0;i<4;++i){
      int row = rbase + mt*16 + qd*4 + i;
      #pragma unroll
      for (int nt=0;nt<4;++nt){
        out[(size_t)row*DIMX + cbase + nt*16 + lm] = acc[mt][nt][i] + bv[nt];
      }
    }
  }
}

// ----------------------------------------------------------------- launch

extern "C" void kernel_launch(void* const* d_in, const int* in_sizes, int n_in,
                              void* d_out, int out_size, void* d_ws, size_t ws_size,
                              hipStream_t stream) {
  (void)in_sizes; (void)n_in; (void)out_size;
  const float* q     = (const float*)d_in[0];
  const float* k     = (const float*)d_in[1];
  const float* v     = (const float*)d_in[2];
  const float* ln_g  = (const float*)d_in[3];
  const float* ln_b  = (const float*)d_in[4];
  const float* W_in  = (const float*)d_in[5];
  const float* wp_W1 = (const float*)d_in[6];
  const float* wp_b1 = (const float*)d_in[7];
  const float* wp_lg = (const float*)d_in[8];
  const float* wp_lb = (const float*)d_in[9];
  const float* wp_W2 = (const float*)d_in[10];
  const float* wp_b2 = (const float*)d_in[11];
  const float* wp_W3 = (const float*)d_in[12];
  const float* wp_b3 = (const float*)d_in[13];
  const float* wtemp = (const float*)d_in[14];
  const float* W_out = (const float*)d_in[15];
  const float* b_out = (const float*)d_in[16];
  float* out = (float*)d_out;

  char* wsb = (char*)d_ws;
  double* gacc = (double*)wsb;            // 24 doubles
  double* racc = gacc + 24;               // 48
  double* qgs  = racc + 48;               // 512
  double* kgs  = qgs + 512;               // 512  (zone0 total < 16384)
  float* fvA = (float*)(wsb + 16384);     // 8 MB; reused as ohh/ohl after k_vT
  unsigned short* ohh = (unsigned short*)fvA;                   // 4 MB
  unsigned short* ohl = ohh + (size_t)NQB*NTOK*NH*DH;           // 4 MB
  float* mu_rstd = fvA + (size_t)NPAIR*NTOK*DH;   // 24576
  float* nuA  = mu_rstd + 24576;          // 2048
  float* Sarr = nuA + 2048;               // 64 (padded)
  float* inv_na_q = Sarr + 64;
  float* muqA     = inv_na_q + NROWS;
  float* tqA      = muqA + NROWS;
  float* inv_na_k = tqA + NROWS;
  float* skA      = inv_na_k + NROWS;
  float* var_row  = skA + NROWS;
  float* mxcos    = var_row + NROWS;
  float* mncos    = mxcos + NROWS;
  float* mxcov    = mncos + NROWS;
  float* mncov    = mxcov + NROWS;
  float* rsPcos   = mncov + NROWS;        // [NROWS][2]
  float* rsPcov   = rsPcos + (size_t)NROWS*2;
  float* rsPmarg  = rsPcov + (size_t)NROWS*2;
  float* mxP      = rsPmarg + (size_t)NROWS*2;
  float* mnP      = mxP + (size_t)NROWS*2;
  float* xvP      = mnP + (size_t)NROWS*2;
  float* nvP      = xvP + (size_t)NROWS*2;
  float* wp_out   = nvP + (size_t)NROWS*2;  // 32 (padded)
  float* coef     = wp_out + 32;            // 32 (padded)
  float* endf     = coef + 32;
  size_t off16 = (size_t)((char*)endf - wsb);
  off16 = (off16 + 63) & ~(size_t)63;
  unsigned short* fqh  = (unsigned short*)(wsb + off16);
  unsigned short* fql  = fqh  + (size_t)NPAIR*NTOK*DH;
  unsigned short* fkh  = fql  + (size_t)NPAIR*NTOK*DH;
  unsigned short* fkl  = fkh  + (size_t)NPAIR*NTOK*DH;
  unsigned short* fvTh = fkl  + (size_t)NPAIR*NTOK*DH;
  unsigned short* fvTl = fvTh + (size_t)NPAIR*NTOK*DH;
  unsigned short* Wth  = fvTl + (size_t)NPAIR*NTOK*DH;
  unsigned short* Wtl  = Wth  + (size_t)DIMX*DIMX;
  unsigned short* Woth = Wtl  + (size_t)DIMX*DIMX;
  unsigned short* Wotl = Woth + (size_t)DIMX*DIMX;
  float* pO   = (float*)(Wotl + (size_t)DIMX*DIMX);   // 32768*2*64 floats = 16.8 MB
  float* pden = pO + (size_t)NROWS*2*DH;              // 65536 floats
  size_t need = (size_t)((char*)(pden + (size_t)NROWS*2) - wsb);
  if (ws_size < need) return;  // fail cleanly rather than corrupt

  hipMemsetAsync(wsb, 0, 16384, stream);
  k_lnstats<<<3072, 256, 0, stream>>>(q, k, v, mu_rstd);
  k_splitW<<<dim3(8,8,2), 256, 0, stream>>>(W_in, W_out, Wth, Wtl, Woth, Wotl);
  k_projmm<<<dim3(64,4,3), 256, 0, stream>>>(q, k, v, ln_g, ln_b, Wth, Wtl,
                                             mu_rstd, fqh, fql, fkh, fkl, fvA,
                                             qgs, kgs);
  k_vT<<<dim3(16,32), 256, 0, stream>>>(fvA, fvTh, fvTl);
  k_nu<<<32, 256, 0, stream>>>(fkh, fkl, nuA, Sarr);
  k_rows<<<8192, 256, 0, stream>>>(fqh, fql, fkh, fkl, nuA,
                                   inv_na_q, muqA, tqA, inv_na_k, skA);
  k_wp<<<1, 256, 0, stream>>>(qgs, kgs, wp_W1, wp_b1, wp_lg, wp_lb,
                              wp_W2, wp_b2, wp_W3, wp_b3, wtemp, wp_out);
  k_passA<<<2048, 256, 0, stream>>>(fqh, fql, fkh, fkl,
                                    inv_na_q, muqA, tqA, inv_na_k, skA, Sarr,
                                    rsPcos, rsPcov, rsPmarg,
                                    mxP, mnP, xvP, nvP, gacc);
  k_rowfin<<<128, 256, 0, stream>>>(rsPcos, rsPcov, rsPmarg, mxP, mnP, xvP, nvP,
                                    var_row, mxcos, mncos, mxcov, mncov, racc);
  k_final<<<1, 64, 0, stream>>>(gacc, racc, wp_out, coef);
  k_pv<<<2048, 256, 0, stream>>>(fqh, fql, fkh, fkl, fvTh, fvTl,
                                 inv_na_q, muqA, tqA, inv_na_k, skA, Sarr,
                                 var_row, mxcos, mncos, mxcov, mncov, coef,
                                 pO, pden);
  k_pvred<<<8192, 256, 0, stream>>>(pO, pden, ohh, ohl);
  k_outmm<<<dim3(64,4), 256, 0, stream>>>(ohh, ohl, Woth, Wotl, b_out, out);
}

// Round 8
// 384.400 us; speedup vs baseline: 1.3994x; 1.3994x over previous
//
#include <hip/hip_runtime.h>
#include <math.h>

#define NH    8
#define NQB   4
#define NPAIR 32
#define NTOK  1024
#define DH    64
#define DIMX  512
#define NROWS (NPAIR*NTOK)

typedef __attribute__((ext_vector_type(8))) short short8;
typedef _Float16 half8 __attribute__((ext_vector_type(8)));
typedef __attribute__((ext_vector_type(4))) float f32x4;

__device__ __forceinline__ unsigned short f2bf(float x){
  unsigned u = __float_as_uint(x);
  u += 0x7fffu + ((u>>16)&1u);
  return (unsigned short)(u>>16);
}
__device__ __forceinline__ float bf2f(unsigned short h){
  return __uint_as_float(((unsigned)h)<<16);
}
__device__ __forceinline__ unsigned short f2h(float x){
  union{ _Float16 f; unsigned short u; } c; c.f = (_Float16)x; return c.u;
}
__device__ __forceinline__ float h2f(unsigned short u){
  union{ _Float16 f; unsigned short u; } c; c.u = u; return (float)c.f;
}
__device__ __forceinline__ f32x4 mfma16(short8 a, short8 b, f32x4 c){
  return __builtin_amdgcn_mfma_f32_16x16x32_bf16(a,b,c,0,0,0);
}
__device__ __forceinline__ f32x4 mfma16f(half8 a, half8 b, f32x4 c){
  return __builtin_amdgcn_mfma_f32_16x16x32_f16(a,b,c,0,0,0);
}
// async global->LDS DMA, 16B per lane; LDS dest = base + lane*16
__device__ __forceinline__ void dma16(const void* g, void* l){
  __builtin_amdgcn_global_load_lds(
      (const __attribute__((address_space(1))) void*)g,
      (__attribute__((address_space(3))) void*)l, 16, 0, 0);
}

// K layout: FK[p][kc][dq][k64][8]: idx = (((p*16+kc)*8+dq)*64 + k64)*8 + dr
__device__ __forceinline__ size_t kidx(int p, int key, int dh){
  return ((((size_t)(p*16 + (key>>6)))*8 + (dh>>3))*64 + (key&63))*8 + (dh&7);
}

// ------------------------------------------------- per-token LN statistics

__global__ __launch_bounds__(256) void k_lnstats(const float* __restrict__ q,
    const float* __restrict__ k, const float* __restrict__ v,
    float* __restrict__ mu_rstd){
  int wid = threadIdx.x >> 6, lane = threadIdx.x & 63;
  int tok = blockIdx.x*4 + wid;            // 0..12287
  const float* src = (tok < 4096) ? q : ((tok < 8192) ? k : v);
  int t = tok & 4095;
  const float4* p4 = (const float4*)(src + (size_t)t*DIMX) + lane*2;
  float4 a = p4[0], b = p4[1];
  float s  = a.x+a.y+a.z+a.w + b.x+b.y+b.z+b.w;
  float ss = a.x*a.x+a.y*a.y+a.z*a.z+a.w*a.w
           + b.x*b.x+b.y*b.y+b.z*b.z+b.w*b.w;
  #pragma unroll
  for (int off=32; off; off>>=1){ s += __shfl_down(s,off); ss += __shfl_down(ss,off); }
  if (lane==0){
    float mu = s*(1.0f/512.0f);
    float var = ss*(1.0f/512.0f) - mu*mu;
    mu_rstd[tok*2+0] = mu;
    mu_rstd[tok*2+1] = 1.0f/sqrtf(var + 1e-5f);
  }
}

// ---------------- transpose + hi/lo split of W_in and W_out -> [n][k] bf16

__global__ __launch_bounds__(256) void k_splitW(const float* __restrict__ Wa,
    const float* __restrict__ Wb,
    unsigned short* __restrict__ Wth, unsigned short* __restrict__ Wtl,
    unsigned short* __restrict__ Woth, unsigned short* __restrict__ Wotl){
  __shared__ float tile[64][65];
  int z = blockIdx.z;
  const float* W = z ? Wb : Wa;
  unsigned short* oh_ = z ? Woth : Wth;
  unsigned short* ol_ = z ? Wotl : Wtl;
  int kb = blockIdx.x, nb = blockIdx.y, tid = threadIdx.x;
  #pragma unroll
  for (int it=0; it<4; ++it){
    int idx = tid + 256*it;          // 0..1023
    int kr = idx>>4, c4 = idx&15;
    float4 vv = *(const float4*)(W + (size_t)(kb*64+kr)*DIMX + nb*64 + c4*4);
    tile[c4*4+0][kr]=vv.x; tile[c4*4+1][kr]=vv.y; tile[c4*4+2][kr]=vv.z; tile[c4*4+3][kr]=vv.w;
  }
  __syncthreads();
  #pragma unroll
  for (int it=0; it<4; ++it){
    int idx = tid + 256*it;
    int n = idx>>4, k4 = idx&15;
    size_t base = (size_t)(nb*64+n)*DIMX + kb*64 + k4*4;
    ushort4 hv, lv;
    { float xx=tile[n][k4*4+0]; unsigned short hh=f2bf(xx); hv.x=hh; lv.x=f2bf(xx-bf2f(hh)); }
    { float xx=tile[n][k4*4+1]; unsigned short hh=f2bf(xx); hv.y=hh; lv.y=f2bf(xx-bf2f(hh)); }
    { float xx=tile[n][k4*4+2]; unsigned short hh=f2bf(xx); hv.z=hh; lv.z=f2bf(xx-bf2f(hh)); }
    { float xx=tile[n][k4*4+3]; unsigned short hh=f2bf(xx); hv.w=hh; lv.w=f2bf(xx-bf2f(hh)); }
    *(ushort4*)(oh_+base) = hv;
    *(ushort4*)(ol_+base) = lv;
  }
}

// --------------- LN + projection GEMM via split-bf16 MFMA (q, k, v by z)

__global__ __launch_bounds__(256) void k_projmm(
    const float* __restrict__ q, const float* __restrict__ k, const float* __restrict__ v,
    const float* __restrict__ g, const float* __restrict__ bln,
    const unsigned short* __restrict__ Wth, const unsigned short* __restrict__ Wtl,
    const float* __restrict__ mu_rstd,
    unsigned short* __restrict__ fqh, unsigned short* __restrict__ fql,
    unsigned short* __restrict__ fkh, unsigned short* __restrict__ fkl,
    float* __restrict__ fv,
    double* __restrict__ qgs, double* __restrict__ kgs){
  __shared__ __align__(16) unsigned short Ahs[64*72];
  __shared__ __align__(16) unsigned short Als[64*72];
  __shared__ float scrc[4][128];
  int z = blockIdx.z;
  const float* x = (z==0) ? q : ((z==1) ? k : v);
  int mb = blockIdx.x, nb = blockIdx.y;
  int tid = threadIdx.x, w = tid>>6, l = tid&63, lm = l&15, qd = l>>4;
  int rbase = (w&1)*32;
  int cbase = nb*128 + (w>>1)*64;
  scrc[tid>>7][tid&127] = 0.f;
  scrc[2+(tid>>7)][tid&127] = 0.f;
  f32x4 acc[2][4];
  #pragma unroll
  for (int mt=0;mt<2;++mt)
    #pragma unroll
    for (int nt=0;nt<4;++nt) acc[mt][nt] = (f32x4){0.f,0.f,0.f,0.f};
  for (int kc8 = 0; kc8 < 8; ++kc8){
    float4 xv[4]; float mus[4], rss[4]; float4 gv[4], bv[4]; int rr[4], kk4[4];
    #pragma unroll
    for (int it=0; it<4; ++it){
      int idx = tid + 256*it;          // 0..1023
      int r = idx>>4, k4 = idx&15;
      rr[it]=r; kk4[it]=k4;
      int tokg = z*4096 + mb*64 + r;
      mus[it] = mu_rstd[tokg*2+0]; rss[it] = mu_rstd[tokg*2+1];
      xv[it] = *(const float4*)(x + (size_t)(mb*64+r)*DIMX + kc8*64 + k4*4);
      gv[it] = *(const float4*)(g   + kc8*64 + k4*4);
      bv[it] = *(const float4*)(bln + kc8*64 + k4*4);
    }
    __syncthreads();
    #pragma unroll
    for (int it=0; it<4; ++it){
      float y0 = (xv[it].x-mus[it])*rss[it]*gv[it].x + bv[it].x;
      float y1 = (xv[it].y-mus[it])*rss[it]*gv[it].y + bv[it].y;
      float y2 = (xv[it].z-mus[it])*rss[it]*gv[it].z + bv[it].z;
      float y3 = (xv[it].w-mus[it])*rss[it]*gv[it].w + bv[it].w;
      ushort4 hv, lv;
      { unsigned short hh=f2bf(y0); hv.x=hh; lv.x=f2bf(y0-bf2f(hh)); }
      { unsigned short hh=f2bf(y1); hv.y=hh; lv.y=f2bf(y1-bf2f(hh)); }
      { unsigned short hh=f2bf(y2); hv.z=hh; lv.z=f2bf(y2-bf2f(hh)); }
      { unsigned short hh=f2bf(y3); hv.w=hh; lv.w=f2bf(y3-bf2f(hh)); }
      *(ushort4*)(Ahs + rr[it]*72 + kk4[it]*4) = hv;
      *(ushort4*)(Als + rr[it]*72 + kk4[it]*4) = lv;
    }
    __syncthreads();
    #pragma unroll
    for (int kch=0; kch<2; ++kch){
      short8 a_h[2], a_l[2];
      #pragma unroll
      for (int mt=0;mt<2;++mt){
        a_h[mt] = *(const short8*)(Ahs + (rbase+mt*16+lm)*72 + kch*32 + qd*8);
        a_l[mt] = *(const short8*)(Als + (rbase+mt*16+lm)*72 + kch*32 + qd*8);
      }
      #pragma unroll
      for (int nt=0;nt<4;++nt){
        int cg = cbase + nt*16 + lm;
        size_t wix = (size_t)cg*DIMX + kc8*64 + kch*32 + qd*8;
        short8 bh = *(const short8*)(Wth + wix);
        short8 bl = *(const short8*)(Wtl + wix);
        #pragma unroll
        for (int mt=0;mt<2;++mt){
          acc[mt][nt] = mfma16(a_h[mt], bh, acc[mt][nt]);
          acc[mt][nt] = mfma16(a_h[mt], bl, acc[mt][nt]);
          acc[mt][nt] = mfma16(a_l[mt], bh, acc[mt][nt]);
        }
      }
    }
  }
  int head = cbase >> 6;
  if (z < 2){
    float csum[4] = {0.f,0.f,0.f,0.f};
    #pragma unroll
    for (int mt=0;mt<2;++mt){
      #pragma unroll
      for (int nt=0;nt<4;++nt){
        #pragma unroll
        for (int i=0;i<4;++i){
          float val = acc[mt][nt][i];
          csum[nt] += val;
          int tglob = mb*64 + rbase + mt*16 + qd*4 + i;
          int qb = tglob>>10, n = tglob&1023;
          int p = head*4 + qb;
          int d = nt*16 + lm;
          unsigned short hh = f2bf(val);
          unsigned short ll = f2bf(val - bf2f(hh));
          if (z==0){
            size_t ix = ((size_t)(p*NTOK+n))*DH + d;
            fqh[ix] = hh; fql[ix] = ll;
          } else {
            size_t ix = kidx(p, n, d);
            fkh[ix] = hh; fkl[ix] = ll;
          }
        }
      }
    }
    #pragma unroll
    for (int m=16;m<64;m<<=1){
      #pragma unroll
      for (int nt=0;nt<4;++nt) csum[nt] += __shfl_xor(csum[nt], m);
    }
    if (qd==0){
      #pragma unroll
      for (int nt=0;nt<4;++nt) scrc[w][(w>>1)*64 + nt*16 + lm] = csum[nt];
    }
    __syncthreads();
    if (tid < 128){
      float s = scrc[0][tid]+scrc[1][tid]+scrc[2][tid]+scrc[3][tid];
      double* dst = (z==0) ? qgs : kgs;
      atomicAdd(&dst[nb*128 + tid], (double)s);
    }
  } else {
    #pragma unroll
    for (int mt=0;mt<2;++mt){
      #pragma unroll
      for (int nt=0;nt<4;++nt){
        #pragma unroll
        for (int i=0;i<4;++i){
          int tglob = mb*64 + rbase + mt*16 + qd*4 + i;
          int qb = tglob>>10, n = tglob&1023;
          int p = head*4 + qb;
          int d = nt*16 + lm;
          fv[((size_t)(p*NTOK+n))*DH + d] = acc[mt][nt][i];
        }
      }
    }
  }
}

// ------- transpose fv -> fvT (fp16 hi/lo, chunk layout [p][kc][kq][d][8])

__global__ __launch_bounds__(256) void k_vT(const float* __restrict__ fv,
    unsigned short* __restrict__ fvTh, unsigned short* __restrict__ fvTl){
  __shared__ float tile[64][65];
  int mc = blockIdx.x, p = blockIdx.y, tid = threadIdx.x;
  #pragma unroll
  for (int it=0; it<4; ++it){
    int idx = tid + 256*it;
    int m = idx>>4, d4 = idx&15;
    float4 vv = *(const float4*)(fv + ((size_t)(p*NTOK + mc*64 + m)*DH + d4*4));
    tile[d4*4+0][m]=vv.x; tile[d4*4+1][m]=vv.y; tile[d4*4+2][m]=vv.z; tile[d4*4+3][m]=vv.w;
  }
  __syncthreads();
  #pragma unroll
  for (int it=0; it<2; ++it){
    int idx = tid + 256*it;       // 0..511
    int d = idx>>3, seg = idx&7;  // keys seg*8..seg*8+8
    size_t base = ((((size_t)(p*16+mc))*8 + seg)*64 + d)*8;
    ushort4 h0,h1,l0,l1;
    { float xx=tile[d][seg*8+0]; unsigned short hh=f2h(xx); h0.x=hh; l0.x=f2h(xx-h2f(hh)); }
    { float xx=tile[d][seg*8+1]; unsigned short hh=f2h(xx); h0.y=hh; l0.y=f2h(xx-h2f(hh)); }
    { float xx=tile[d][seg*8+2]; unsigned short hh=f2h(xx); h0.z=hh; l0.z=f2h(xx-h2f(hh)); }
    { float xx=tile[d][seg*8+3]; unsigned short hh=f2h(xx); h0.w=hh; l0.w=f2h(xx-h2f(hh)); }
    { float xx=tile[d][seg*8+4]; unsigned short hh=f2h(xx); h1.x=hh; l1.x=f2h(xx-h2f(hh)); }
    { float xx=tile[d][seg*8+5]; unsigned short hh=f2h(xx); h1.y=hh; l1.y=f2h(xx-h2f(hh)); }
    { float xx=tile[d][seg*8+6]; unsigned short hh=f2h(xx); h1.z=hh; l1.z=f2h(xx-h2f(hh)); }
    { float xx=tile[d][seg*8+7]; unsigned short hh=f2h(xx); h1.w=hh; l1.w=f2h(xx-h2f(hh)); }
    *(ushort4*)(fvTh+base)   = h0;
    *(ushort4*)(fvTh+base+4) = h1;
    *(ushort4*)(fvTl+base)   = l0;
    *(ushort4*)(fvTl+base+4) = l1;
  }
}

// -------------------------------------------- nu (col-means of f_k) and S

__global__ __launch_bounds__(256) void k_nu(const unsigned short* __restrict__ fkh,
    const unsigned short* __restrict__ fkl,
    float* __restrict__ nuA, float* __restrict__ Sarr){
  __shared__ float red[4][64];
  int p = blockIdx.x, tid = threadIdx.x;
  int td = tid & 63, tm = tid >> 6;
  float s = 0.f;
  for (int m = tm; m < NTOK; m += 4){
    size_t ix = kidx(p, m, td);
    s += bf2f(fkh[ix]) + bf2f(fkl[ix]);
  }
  red[tm][td] = s;
  __syncthreads();
  if (tid < 64){
    float tot = red[0][tid]+red[1][tid]+red[2][tid]+red[3][tid];
    float nuv = tot * (1.0f/1024.0f);
    nuA[p*DH+tid] = nuv;
    float sv = nuv;
    #pragma unroll
    for (int off=32; off; off>>=1) sv += __shfl_down(sv, off);
    if (tid==0) Sarr[p] = sv;
  }
}

// --------------------------------------- per-row scalars for f_q and f_k

__global__ __launch_bounds__(256) void k_rows(
    const unsigned short* __restrict__ fqh, const unsigned short* __restrict__ fql,
    const unsigned short* __restrict__ fkh, const unsigned short* __restrict__ fkl,
    const float* __restrict__ nuA,
    float* __restrict__ inv_na_q, float* __restrict__ muqA, float* __restrict__ tqA,
    float* __restrict__ inv_na_k, float* __restrict__ skA){
  int wid = threadIdx.x >> 6, lane = threadIdx.x & 63;
  int row = blockIdx.x*4 + wid;            // < 32768
  int p = row >> 10;
  int key = row & 1023;
  size_t ix = (size_t)row*DH + lane;
  float xq = bf2f(fqh[ix]) + bf2f(fql[ix]);
  float nv = nuA[p*DH + lane];
  float s = xq, ss = xq*xq, sd = xq*nv;
  #pragma unroll
  for (int off=32; off; off>>=1){
    s += __shfl_down(s,off); ss += __shfl_down(ss,off); sd += __shfl_down(sd,off);
  }
  if (lane==0){
    float nrm = sqrtf(ss);
    inv_na_q[row] = 1.0f/(nrm+1e-8f);
    muqA[row] = s*(1.0f/64.0f);
    tqA[row] = sd;
  }
  size_t ixk = kidx(p, key, lane);
  float xk = bf2f(fkh[ixk]) + bf2f(fkl[ixk]);
  float s2 = xk, ss2 = xk*xk;
  #pragma unroll
  for (int off=32; off; off>>=1){
    s2 += __shfl_down(s2,off); ss2 += __shfl_down(ss2,off);
  }
  if (lane==0){
    float nrm = sqrtf(ss2);
    inv_na_k[row] = 1.0f/(nrm+1e-8f);
    skA[row] = s2;
  }
}

// ------------------------------------------------- weight predictor (tiny)

__global__ __launch_bounds__(256) void k_wp(const double* __restrict__ qgs,
    const double* __restrict__ kgs,
    const float* __restrict__ W1, const float* __restrict__ b1,
    const float* __restrict__ lgv, const float* __restrict__ lbv,
    const float* __restrict__ W2, const float* __restrict__ b2,
    const float* __restrict__ W3, const float* __restrict__ b3,
    const float* __restrict__ wtemp, float* __restrict__ wp_out){
  __shared__ float feats[8][128];
  __shared__ float h1[8][64];
  __shared__ float h2s[8][32];
  __shared__ float lgt[8][3];
  __shared__ float mv[8][2];
  int tid = threadIdx.x;
  for (int idx = tid; idx < 1024; idx += 256){
    int h = idx >> 7, i = idx & 127;
    double vv = (i < 64) ? qgs[h*64+i] : kgs[h*64+(i-64)];
    feats[h][i] = (float)(vv * (1.0/4096.0));
  }
  __syncthreads();
  for (int idx = tid; idx < 512; idx += 256){
    int h = idx >> 6, j = idx & 63;
    float s = b1[j];
    for (int i = 0; i < 128; ++i) s += feats[h][i]*W1[i*64+j];
    h1[h][j] = s;
  }
  __syncthreads();
  if (tid < 8){
    float s=0.f, ss=0.f;
    for (int j=0;j<64;++j){ float vv=h1[tid][j]; s+=vv; ss+=vv*vv; }
    float mu = s*(1.0f/64.0f);
    float var = ss*(1.0f/64.0f)-mu*mu;
    mv[tid][0]=mu; mv[tid][1]=1.0f/sqrtf(var+1e-5f);
  }
  __syncthreads();
  for (int idx = tid; idx < 512; idx += 256){
    int h = idx>>6, j = idx&63;
    float vv = (h1[h][j]-mv[h][0])*mv[h][1]*lgv[j] + lbv[j];
    h1[h][j] = fmaxf(vv, 0.f);
  }
  __syncthreads();
  {
    int h = tid >> 5, j = tid & 31;
    float s = b2[j];
    for (int i=0;i<64;++i) s += h1[h][i]*W2[i*32+j];
    h2s[h][j] = fmaxf(s, 0.f);
  }
  __syncthreads();
  if (tid < 24){
    int h = tid/3, j = tid - h*3;
    float s = b3[j];
    for (int i=0;i<32;++i) s += h2s[h][i]*W3[i*3+j];
    lgt[h][j] = s;
  }
  __syncthreads();
  if (tid < 8){
    int h = tid;
    float z0=lgt[h][0], z1=lgt[h][1], z2=lgt[h][2];
    float m = fmaxf(z0,fmaxf(z1,z2));
    float e0=expf(z0-m), e1=expf(z1-m), e2=expf(z2-m);
    float inv = 1.0f/(e0+e1+e2);
    float l0=e0*inv, l1=e1*inv, l2=e2*inv;
    float wt = fminf(fmaxf(wtemp[0], 0.1f), 20.0f);
    float y0=l0/wt, y1=l1/wt, y2=l2/wt;
    float m2 = fmaxf(y0,fmaxf(y1,y2));
    float f0=expf(y0-m2), f1=expf(y1-m2), f2=expf(y2-m2);
    float inv2 = 1.0f/(f0+f1+f2);
    float w0=f0*inv2, w1=f1*inv2, w2=f2*inv2;
    w0 = fminf(fmaxf(w0,0.05f),0.8f);
    w1 = fminf(fmaxf(w1,0.05f),0.8f);
    w2 = fminf(fmaxf(w2,0.05f),0.8f);
    float isum = 1.0f/(w0+w1+w2);
    wp_out[h*3+0]=w0*isum; wp_out[h*3+1]=w1*isum; wp_out[h*3+2]=w2*isum;
  }
}

// ------------- pass A (MFMA): K staged via global_load_lds; QK + stats.
// grid 1024: block = 32 rows x 1024 keys; wave = (row half, key half of chunk)

__global__ __launch_bounds__(256) void k_passA(
    const unsigned short* __restrict__ fqh, const unsigned short* __restrict__ fql,
    const unsigned short* __restrict__ fkh, const unsigned short* __restrict__ fkl,
    const float* __restrict__ inv_na_q, const float* __restrict__ muqA,
    const float* __restrict__ tqA,
    const float* __restrict__ inv_na_k, const float* __restrict__ skA,
    const float* __restrict__ Sarr,
    float* __restrict__ rs_cos, float* __restrict__ rs_cov, float* __restrict__ rs_marg,
    float* __restrict__ mxcosA, float* __restrict__ mncosA,
    float* __restrict__ mxcovA, float* __restrict__ mncovA,
    double* __restrict__ gacc){
  __shared__ __align__(16) unsigned short Kh[4096];
  __shared__ __align__(16) unsigned short Kl[4096];
  __shared__ float redbuf[4][16][7];
  __shared__ double wredS[4][3];
  int b = blockIdx.x;
  int p = ((b&7)<<2) | ((b>>3)&3);   // XCD swizzle
  int s = b>>5;                      // 0..31
  int n0 = s*32;
  int tid = threadIdx.x, w = tid>>6, l = tid&63;
  int lm = l&15, q = l>>4;
  int rt = w&1, cw = w>>1;
  int nw = n0 + rt*16;
  float Sp = Sarr[p];
  const float inv8 = (float)(1.0/(8.0+1e-6));
  float ia[4], m8[4], t8[4];
  #pragma unroll
  for (int i=0;i<4;++i){
    int rg = p*NTOK + nw + q*4 + i;
    float mq = muqA[rg];
    ia[i] = inv_na_q[rg];
    m8[i] = mq*inv8;
    t8[i] = (tqA[rg] - mq*Sp)*inv8;
  }
  const short8* aqh = (const short8*)(fqh + (size_t)(p*NTOK + nw + lm)*DH);
  const short8* aql = (const short8*)(fql + (size_t)(p*NTOK + nw + lm)*DH);
  short8 ah0 = aqh[q], ah1 = aqh[4+q], al0 = aql[q], al1 = aql[4+q];
  const unsigned short* gKh = fkh + (size_t)p*16*4096;
  const unsigned short* gKl = fkl + (size_t)p*16*4096;
  const float* cAg = inv_na_k + p*NTOK;
  const float* cSg = skA + p*NTOK;
  float sc2=0.f, sv2=0.f, scv=0.f;
  float pc[4]={0,0,0,0}, pv_[4]={0,0,0,0}, pm[4]={0,0,0,0};
  float xc[4], nc[4], xv[4], nv[4];
  #pragma unroll
  for (int i=0;i<4;++i){ xc[i]=-1e30f; nc[i]=1e30f; xv[i]=-1e30f; nv[i]=1e30f; }
  for (int cc=0; cc<16; ++cc){
    __syncthreads();                 // previous chunk fully consumed
    {
      int r = w*2;
      const unsigned short* cb = gKh + cc*4096;
      dma16(cb + (r  )*512 + l*8, &Kh[(r  )*512]);
      dma16(cb + (r+1)*512 + l*8, &Kh[(r+1)*512]);
      cb = gKl + cc*4096;
      dma16(cb + (r  )*512 + l*8, &Kl[(r  )*512]);
      dma16(cb + (r+1)*512 + l*8, &Kl[(r+1)*512]);
    }
    __syncthreads();                 // staged data visible
    #pragma unroll
    for (int t2=0; t2<2; ++t2){
      int c16 = cw*2 + t2;
      short8 kh0 = *(const short8*)&Kh[((q  )*64 + c16*16+lm)*8];
      short8 kh1 = *(const short8*)&Kh[((q+4)*64 + c16*16+lm)*8];
      short8 kl0 = *(const short8*)&Kl[((q  )*64 + c16*16+lm)*8];
      short8 kl1 = *(const short8*)&Kl[((q+4)*64 + c16*16+lm)*8];
      f32x4 acc = {0.f,0.f,0.f,0.f};
      acc = mfma16(ah0,kh0,acc); acc = mfma16(ah1,kh1,acc);
      acc = mfma16(al0,kh0,acc); acc = mfma16(al1,kh1,acc);
      acc = mfma16(ah0,kl0,acc); acc = mfma16(ah1,kl1,acc);
      int colg = cc*64 + c16*16 + lm;
      float ca = cAg[colg], cs = cSg[colg];
      #pragma unroll
      for (int i=0;i<4;++i){
        float dot = acc[i];
        float cosv = fminf(fmaxf(dot*ia[i]*ca,-0.99f),0.99f);
        float cov  = fmaf(-m8[i], cs, fmaf(dot, inv8, -t8[i]));
        float marg = fmaxf(0.01f - cosv, 0.f);
        sc2 = fmaf(cosv,cosv,sc2); sv2 = fmaf(cov,cov,sv2); scv = fmaf(cosv,cov,scv);
        pc[i]+=cosv; pv_[i]+=cov; pm[i]+=marg;
        xc[i]=fmaxf(xc[i],cosv); nc[i]=fminf(nc[i],cosv);
        xv[i]=fmaxf(xv[i],cov);  nv[i]=fminf(nv[i],cov);
      }
    }
  }
  #pragma unroll
  for (int m=1;m<16;m<<=1){
    #pragma unroll
    for (int i=0;i<4;++i){
      pc[i]+=__shfl_xor(pc[i],m); pv_[i]+=__shfl_xor(pv_[i],m); pm[i]+=__shfl_xor(pm[i],m);
      xc[i]=fmaxf(xc[i],__shfl_xor(xc[i],m)); nc[i]=fminf(nc[i],__shfl_xor(nc[i],m));
      xv[i]=fmaxf(xv[i],__shfl_xor(xv[i],m)); nv[i]=fminf(nv[i],__shfl_xor(nv[i],m));
    }
  }
  if (lm==0){
    #pragma unroll
    for (int i=0;i<4;++i){
      int r16 = q*4+i;
      redbuf[w][r16][0]=pc[i]; redbuf[w][r16][1]=pv_[i]; redbuf[w][r16][2]=pm[i];
      redbuf[w][r16][3]=xc[i]; redbuf[w][r16][4]=nc[i];
      redbuf[w][r16][5]=xv[i]; redbuf[w][r16][6]=nv[i];
    }
  }
  double vals[3] = {(double)sc2,(double)sv2,(double)scv};
  #pragma unroll
  for (int c2=0;c2<3;++c2){
    double vv = vals[c2];
    #pragma unroll
    for (int off=32; off; off>>=1) vv += __shfl_down(vv, off);
    if (l==0) wredS[w][c2] = vv;
  }
  __syncthreads();
  if (tid < 32){
    int rt2 = tid>>4, r16 = tid&15;
    int w0 = rt2, w1 = rt2+2;          // two key-half waves of this row half
    float sc = redbuf[w0][r16][0]+redbuf[w1][r16][0];
    float sv = redbuf[w0][r16][1]+redbuf[w1][r16][1];
    float sm = redbuf[w0][r16][2]+redbuf[w1][r16][2];
    float mxc = fmaxf(redbuf[w0][r16][3],redbuf[w1][r16][3]);
    float mnc = fminf(redbuf[w0][r16][4],redbuf[w1][r16][4]);
    float mxv = fmaxf(redbuf[w0][r16][5],redbuf[w1][r16][5]);
    float mnv = fminf(redbuf[w0][r16][6],redbuf[w1][r16][6]);
    int row = p*NTOK + n0 + tid;
    rs_cos[row]=sc; rs_cov[row]=sv; rs_marg[row]=sm;
    mxcosA[row]=mxc; mncosA[row]=mnc; mxcovA[row]=mxv; mncovA[row]=mnv;
  }
  if (tid == 0){
    int h = p >> 2;
    #pragma unroll
    for (int c2=0;c2<3;++c2){
      double t = wredS[0][c2]+wredS[1][c2]+wredS[2][c2]+wredS[3][c2];
      atomicAdd(&gacc[h*3+c2], t);
    }
  }
}

// ---------------------- row finish: var_row + row-sum-derived moments

__global__ __launch_bounds__(256) void k_rowfin(const float* __restrict__ rs_cos,
    const float* __restrict__ rs_cov, const float* __restrict__ rs_marg,
    float* __restrict__ var_row, double* __restrict__ racc){
  __shared__ double wredS[4][6];
  int row = blockIdx.x*256 + threadIdx.x;
  int p = row >> 10; int h = p >> 2;
  float vr = rs_marg[row] * (1.0f/1024.0f);
  var_row[row] = vr;
  double dv = (double)vr;
  double rc = (double)rs_cos[row], rv = (double)rs_cov[row];
  double vals[6];
  vals[0] = 1024.0*dv;
  vals[1] = 1024.0*dv*dv;
  vals[2] = dv*rc;
  vals[3] = dv*rv;
  vals[4] = rc;
  vals[5] = rv;
  int lane = threadIdx.x & 63, wid = threadIdx.x >> 6;
  #pragma unroll
  for (int c2 = 0; c2 < 6; ++c2){
    double vv = vals[c2];
    #pragma unroll
    for (int off=32; off; off>>=1) vv += __shfl_down(vv, off);
    if (lane==0) wredS[wid][c2] = vv;
  }
  __syncthreads();
  if (threadIdx.x == 0){
    #pragma unroll
    for (int c2 = 0; c2 < 6; ++c2){
      double t = wredS[0][c2]+wredS[1][c2]+wredS[2][c2]+wredS[3][c2];
      atomicAdd(&racc[h*6+c2], t);
    }
  }
}

// ------------------------------------- finalize scalars -> d2 coefficients

__global__ void k_final(const double* __restrict__ gacc, const double* __restrict__ racc,
                        const float* __restrict__ wp_out, float* __restrict__ coef){
  if (threadIdx.x != 0) return;
  const double N = 33554432.0;
  double Sc1=0,Sc2=0,Sv1=0,Sv2=0,Sr1=0,Sr2=0;
  for (int h=0;h<8;++h){
    Sc2+=gacc[h*3+0]; Sv2+=gacc[h*3+1];
    Sr1+=racc[h*6+0]; Sr2+=racc[h*6+1];
    Sc1+=racc[h*6+4]; Sv1+=racc[h*6+5];
  }
  double cvar = (Sc2 - Sc1*Sc1/N)/(N-1.0);
  double cn = sqrt(fmax(cvar,0.0)) + 1e-6;
  double cscale = (cn < 1e-4) ? 0.1 : 1.0;
  double vraw = (Sv2 - Sv1*Sv1/N)/(N-1.0);
  double sraw = sqrt(fmax(vraw,0.0));
  double basev = 0.001/1024.0;
  double regv = (sraw < 1e-6) ? basev*10.0 : basev;
  double covn = regv*sraw + 1e-6;
  double vvar = (Sr2 - Sr1*Sr1/N)/(N-1.0);
  double vn = sqrt(fmax(vvar,0.0)) + 1e-6;
  double ah[8], bh[8], chh[8];
  double Sd1=0.0, Sd2=0.0;
  for (int h=0;h<8;++h){
    double a = (double)wp_out[h*3+0]/cn*cscale;
    double b = (double)wp_out[h*3+1]*regv*0.5/covn;
    double c = (double)wp_out[h*3+2]*0.5/vn;
    ah[h]=a; bh[h]=b; chh[h]=c;
    Sd1 += a*racc[h*6+4] + b*racc[h*6+5] + c*racc[h*6+0];
    Sd2 += a*a*gacc[h*3+0] + b*b*gacc[h*3+1] + c*c*racc[h*6+1]
         + 2.0*(a*b*gacc[h*3+2] + a*c*racc[h*6+2] + b*c*racc[h*6+3]);
  }
  double dvar = (Sd2 - Sd1*Sd1/N)/(N-1.0);
  double dstd = sqrt(fmax(dvar,0.0));
  double temp = (dstd < 1e-6) ? 0.1 : 0.3 + dstd;
  double tcl = fmin(fmax(temp,0.1),5.0);
  double it = 1.0/tcl;
  for (int h=0;h<8;++h){
    coef[h*3+0] = (float)(ah[h]*it);
    coef[h*3+1] = (float)(bh[h]*it);
    coef[h*3+2] = (float)(chh[h]*it);
  }
}

// -------------------- pass C (MFMA): K/V staged via global_load_lds.
// grid 1024: block = 32 rows x 1024 keys; per chunk: DMA, QK+derive+P(LDS),
// PV (fp16 P single, V fp16 hi/lo); direct oh write with inv-den.

__global__ __launch_bounds__(256) void k_pv(
    const unsigned short* __restrict__ fqh, const unsigned short* __restrict__ fql,
    const unsigned short* __restrict__ fkh, const unsigned short* __restrict__ fkl,
    const unsigned short* __restrict__ fvTh, const unsigned short* __restrict__ fvTl,
    const float* __restrict__ inv_na_q, const float* __restrict__ muqA,
    const float* __restrict__ tqA,
    const float* __restrict__ inv_na_k, const float* __restrict__ skA,
    const float* __restrict__ Sarr, const float* __restrict__ var_row,
    const float* __restrict__ mxcosA, const float* __restrict__ mncosA,
    const float* __restrict__ mxcovA, const float* __restrict__ mncovA,
    const float* __restrict__ coef,
    unsigned short* __restrict__ ohh, unsigned short* __restrict__ ohl){
  __shared__ __align__(16) unsigned short Kh[4096];
  __shared__ __align__(16) unsigned short Kl[4096];
  __shared__ __align__(16) unsigned short Vh[4096];
  __shared__ __align__(16) unsigned short Vl[4096];
  __shared__ __align__(16) unsigned short ph[32][72];
  __shared__ float denbuf[4][16];
  __shared__ float dnv[32];
  int b = blockIdx.x;
  int p = ((b&7)<<2) | ((b>>3)&3);   // XCD swizzle
  int s = b>>5;
  int n0 = s*32;
  int h = p>>2, qb = p&3;
  int tid = threadIdx.x, w = tid>>6, l = tid&63;
  int lm = l&15, q = l>>4;
  int rt = w&1, cw = w>>1;
  int nw = n0 + rt*16;
  float A = coef[h*3+0], B = coef[h*3+1], C = coef[h*3+2];
  float Sp = Sarr[p];
  const float inv8 = (float)(1.0/(8.0+1e-6));
  float B8 = B*inv8;
  float ia[4], bm[4], o2[4];
  #pragma unroll
  for (int i=0;i<4;++i){
    int rg = p*NTOK + nw + q*4 + i;
    float mq = muqA[rg];
    ia[i] = inv_na_q[rg];
    bm[i] = B8*mq;
    float tq2 = tqA[rg] - mq*Sp;
    float vr = var_row[rg];
    float Mh = fmaxf(A*mxcosA[rg],A*mncosA[rg]) + fmaxf(B*mxcovA[rg],B*mncovA[rg]) + C*vr;
    o2[i] = (C*vr - Mh) - B8*tq2;
  }
  const short8* aqh = (const short8*)(fqh + (size_t)(p*NTOK + nw + lm)*DH);
  const short8* aql = (const short8*)(fql + (size_t)(p*NTOK + nw + lm)*DH);
  short8 ah0 = aqh[q], ah1 = aqh[4+q], al0 = aql[q], al1 = aql[4+q];
  const unsigned short* gKh = fkh  + (size_t)p*16*4096;
  const unsigned short* gKl = fkl  + (size_t)p*16*4096;
  const unsigned short* gVh = fvTh + (size_t)p*16*4096;
  const unsigned short* gVl = fvTl + (size_t)p*16*4096;
  const float* cAg = inv_na_k + p*NTOK;
  const float* cSg = skA + p*NTOK;
  f32x4 o0 = {0.f,0.f,0.f,0.f}, o1 = {0.f,0.f,0.f,0.f};
  float den[4] = {0.f,0.f,0.f,0.f};
  for (int cc = 0; cc < 16; ++cc){
    __syncthreads();                 // previous chunk (incl. PV reads) done
    {
      int r = w*2;
      const unsigned short* cb = gKh + cc*4096;
      dma16(cb + (r  )*512 + l*8, &Kh[(r  )*512]);
      dma16(cb + (r+1)*512 + l*8, &Kh[(r+1)*512]);
      cb = gKl + cc*4096;
      dma16(cb + (r  )*512 + l*8, &Kl[(r  )*512]);
      dma16(cb + (r+1)*512 + l*8, &Kl[(r+1)*512]);
      cb = gVh + cc*4096;
      dma16(cb + (r  )*512 + l*8, &Vh[(r  )*512]);
      dma16(cb + (r+1)*512 + l*8, &Vh[(r+1)*512]);
      cb = gVl + cc*4096;
      dma16(cb + (r  )*512 + l*8, &Vl[(r  )*512]);
      dma16(cb + (r+1)*512 + l*8, &Vl[(r+1)*512]);
    }
    __syncthreads();                 // staged data visible
    #pragma unroll
    for (int t2=0; t2<2; ++t2){
      int c16 = cw*2 + t2;
      short8 kh0 = *(const short8*)&Kh[((q  )*64 + c16*16+lm)*8];
      short8 kh1 = *(const short8*)&Kh[((q+4)*64 + c16*16+lm)*8];
      short8 kl0 = *(const short8*)&Kl[((q  )*64 + c16*16+lm)*8];
      short8 kl1 = *(const short8*)&Kl[((q+4)*64 + c16*16+lm)*8];
      f32x4 acc = {0.f,0.f,0.f,0.f};
      acc = mfma16(ah0,kh0,acc); acc = mfma16(ah1,kh1,acc);
      acc = mfma16(al0,kh0,acc); acc = mfma16(al1,kh1,acc);
      acc = mfma16(ah0,kl0,acc); acc = mfma16(ah1,kl1,acc);
      int colg = cc*64 + c16*16 + lm;
      float ca = cAg[colg], cs = cSg[colg];
      #pragma unroll
      for (int i=0;i<4;++i){
        float dot = acc[i];
        float cosv = fminf(fmaxf(dot*ia[i]*ca,-0.99f),0.99f);
        float arg = fmaf(A, cosv, fmaf(-bm[i], cs, fmaf(B8, dot, o2[i])));
        float e = __expf(arg);
        unsigned short us = f2h(e);
        ph[rt*16+q*4+i][c16*16+lm] = us;
        den[i] += h2f(us);
      }
    }
    __syncthreads();                 // P complete
    // PV: wave w owns d-range w*16..w*16+16
    {
      half8 vh0 = *(const half8*)&Vh[((q  )*64 + w*16+lm)*8];
      half8 vh1 = *(const half8*)&Vh[((q+4)*64 + w*16+lm)*8];
      half8 vl0 = *(const half8*)&Vl[((q  )*64 + w*16+lm)*8];
      half8 vl1 = *(const half8*)&Vl[((q+4)*64 + w*16+lm)*8];
      half8 pb00 = *(const half8*)&ph[lm][q*8];
      half8 pb01 = *(const half8*)&ph[lm][32+q*8];
      half8 pb10 = *(const half8*)&ph[16+lm][q*8];
      half8 pb11 = *(const half8*)&ph[16+lm][32+q*8];
      o0 = mfma16f(vh0,pb00,o0); o0 = mfma16f(vl0,pb00,o0);
      o0 = mfma16f(vh1,pb01,o0); o0 = mfma16f(vl1,pb01,o0);
      o1 = mfma16f(vh0,pb10,o1); o1 = mfma16f(vl0,pb10,o1);
      o1 = mfma16f(vh1,pb11,o1); o1 = mfma16f(vl1,pb11,o1);
    }
  }
  #pragma unroll
  for (int m=1;m<16;m<<=1){
    #pragma unroll
    for (int i=0;i<4;++i) den[i] += __shfl_xor(den[i],m);
  }
  if (lm==0){
    #pragma unroll
    for (int i=0;i<4;++i) denbuf[w][q*4+i] = den[i];
  }
  __syncthreads();
  if (tid < 32){
    int rt2 = tid>>4, r16 = tid&15;
    dnv[tid] = 1.0f/(denbuf[rt2][r16] + denbuf[rt2+2][r16]);
  }
  __syncthreads();
  {
    float inv0 = dnv[lm];
    float inv1 = dnv[16+lm];
    int d0 = w*16 + q*4;
    size_t b0i = ((size_t)(qb*NTOK + n0 + lm))*(NH*DH) + h*DH + d0;
    size_t b1i = ((size_t)(qb*NTOK + n0 + 16 + lm))*(NH*DH) + h*DH + d0;
    ushort4 h0,l0,h1,l1;
    { float xx=o0[0]*inv0; unsigned short hh=f2bf(xx); h0.x=hh; l0.x=f2bf(xx-bf2f(hh)); }
    { float xx=o0[1]*inv0; unsigned short hh=f2bf(xx); h0.y=hh; l0.y=f2bf(xx-bf2f(hh)); }
    { float xx=o0[2]*inv0; unsigned short hh=f2bf(xx); h0.z=hh; l0.z=f2bf(xx-bf2f(hh)); }
    { float xx=o0[3]*inv0; unsigned short hh=f2bf(xx); h0.w=hh; l0.w=f2bf(xx-bf2f(hh)); }
    { float xx=o1[0]*inv1; unsigned short hh=f2bf(xx); h1.x=hh; l1.x=f2bf(xx-bf2f(hh)); }
    { float xx=o1[1]*inv1; unsigned short hh=f2bf(xx); h1.y=hh; l1.y=f2bf(xx-bf2f(hh)); }
    { float xx=o1[2]*inv1; unsigned short hh=f2bf(xx); h1.z=hh; l1.z=f2bf(xx-bf2f(hh)); }
    { float xx=o1[3]*inv1; unsigned short hh=f2bf(xx); h1.w=hh; l1.w=f2bf(xx-bf2f(hh)); }
    *(ushort4*)(ohh+b0i)=h0; *(ushort4*)(ohl+b0i)=l0;
    *(ushort4*)(ohh+b1i)=h1; *(ushort4*)(ohl+b1i)=l1;
  }
}

// ----------------- output GEMM (MFMA, no LDS): oh @ W_out + b -> out

__global__ __launch_bounds__(256) void k_outmm(
    const unsigned short* __restrict__ ohh, const unsigned short* __restrict__ ohl,
    const unsigned short* __restrict__ Woth, const unsigned short* __restrict__ Wotl,
    const float* __restrict__ bias, float* __restrict__ out){
  int mb = blockIdx.x, nb = blockIdx.y;
  int tid = threadIdx.x, w = tid>>6, l = tid&63, lm = l&15, qd = l>>4;
  int rbase = mb*64 + (w&1)*32;
  int cbase = nb*128 + (w>>1)*64;
  f32x4 acc[2][4];
  #pragma unroll
  for (int mt=0;mt<2;++mt)
    #pragma unroll
    for (int nt=0;nt<4;++nt) acc[mt][nt] = (f32x4){0.f,0.f,0.f,0.f};
  for (int kc=0; kc<16; ++kc){
    short8 a_h[2], a_l[2];
    #pragma unroll
    for (int mt=0;mt<2;++mt){
      size_t aix = (size_t)(rbase+mt*16+lm)*DIMX + kc*32 + qd*8;
      a_h[mt] = *(const short8*)(ohh + aix);
      a_l[mt] = *(const short8*)(ohl + aix);
    }
    #pragma unroll
    for (int nt=0;nt<4;++nt){
      size_t wix = (size_t)(cbase+nt*16+lm)*DIMX + kc*32 + qd*8;
      short8 bh = *(const short8*)(Woth + wix);
      short8 bl = *(const short8*)(Wotl + wix);
      #pragma unroll
      for (int mt=0;mt<2;++mt){
        acc[mt][nt] = mfma16(a_h[mt], bh, acc[mt][nt]);
        acc[mt][nt] = mfma16(a_h[mt], bl, acc[mt][nt]);
        acc[mt][nt] = mfma16(a_l[mt], bh, acc[mt][nt]);
      }
    }
  }
  float bv[4];
  #pragma unroll
  for (int nt=0;nt<4;++nt) bv[nt] = bias[cbase+nt*16+lm];
  #pragma unroll
  for (int mt=0;mt<2;++mt){
    #pragma unroll
    for (int i=0;i<4;++i){
      int row = rbase + mt*16 + qd*4 + i;
      #pragma unroll
      for (int nt=0;nt<4;++nt){
        out[(size_t)row*DIMX + cbase + nt*16 + lm] = acc[mt][nt][i] + bv[nt];
      }
    }
  }
}

// ----------------------------------------------------------------- launch

extern "C" void kernel_launch(void* const* d_in, const int* in_sizes, int n_in,
                              void* d_out, int out_size, void* d_ws, size_t ws_size,
                              hipStream_t stream) {
  (void)in_sizes; (void)n_in; (void)out_size;
  const float* q     = (const float*)d_in[0];
  const float* k     = (const float*)d_in[1];
  const float* v     = (const float*)d_in[2];
  const float* ln_g  = (const float*)d_in[3];
  const float* ln_b  = (const float*)d_in[4];
  const float* W_in  = (const float*)d_in[5];
  const float* wp_W1 = (const float*)d_in[6];
  const float* wp_b1 = (const float*)d_in[7];
  const float* wp_lg = (const float*)d_in[8];
  const float* wp_lb = (const float*)d_in[9];
  const float* wp_W2 = (const float*)d_in[10];
  const float* wp_b2 = (const float*)d_in[11];
  const float* wp_W3 = (const float*)d_in[12];
  const float* wp_b3 = (const float*)d_in[13];
  const float* wtemp = (const float*)d_in[14];
  const float* W_out = (const float*)d_in[15];
  const float* b_out = (const float*)d_in[16];
  float* out = (float*)d_out;

  char* wsb = (char*)d_ws;
  double* gacc = (double*)wsb;            // 24 doubles
  double* racc = gacc + 24;               // 48
  double* qgs  = racc + 48;               // 512
  double* kgs  = qgs + 512;               // 512  (zone0 total < 16384)
  float* fvA = (float*)(wsb + 16384);     // 8 MB; reused as ohh/ohl after k_vT
  unsigned short* ohh = (unsigned short*)fvA;                   // 4 MB
  unsigned short* ohl = ohh + (size_t)NQB*NTOK*NH*DH;           // 4 MB
  float* mu_rstd = fvA + (size_t)NPAIR*NTOK*DH;   // 24576
  float* nuA  = mu_rstd + 24576;          // 2048
  float* Sarr = nuA + 2048;               // 64 (padded)
  float* inv_na_q = Sarr + 64;
  float* muqA     = inv_na_q + NROWS;
  float* tqA      = muqA + NROWS;
  float* inv_na_k = tqA + NROWS;
  float* skA      = inv_na_k + NROWS;
  float* rs_cos   = skA + NROWS;
  float* rs_cov   = rs_cos + NROWS;
  float* rs_marg  = rs_cov + NROWS;
  float* var_row  = rs_marg + NROWS;
  float* mxcos    = var_row + NROWS;
  float* mncos    = mxcos + NROWS;
  float* mxcov    = mncos + NROWS;
  float* mncov    = mxcov + NROWS;
  float* wp_out   = mncov + NROWS;        // 32 (padded)
  float* coef     = wp_out + 32;          // 32 (padded)
  float* endf     = coef + 32;
  size_t off16 = (size_t)((char*)endf - wsb);
  off16 = (off16 + 63) & ~(size_t)63;
  unsigned short* fqh  = (unsigned short*)(wsb + off16);
  unsigned short* fql  = fqh  + (size_t)NPAIR*NTOK*DH;
  unsigned short* fkh  = fql  + (size_t)NPAIR*NTOK*DH;
  unsigned short* fkl  = fkh  + (size_t)NPAIR*NTOK*DH;
  unsigned short* fvTh = fkl  + (size_t)NPAIR*NTOK*DH;
  unsigned short* fvTl = fvTh + (size_t)NPAIR*NTOK*DH;
  unsigned short* Wth  = fvTl + (size_t)NPAIR*NTOK*DH;
  unsigned short* Wtl  = Wth  + (size_t)DIMX*DIMX;
  unsigned short* Woth = Wtl  + (size_t)DIMX*DIMX;
  unsigned short* Wotl = Woth + (size_t)DIMX*DIMX;
  size_t need = (size_t)((char*)(Wotl + (size_t)DIMX*DIMX) - wsb);
  if (ws_size < need) return;  // fail cleanly rather than corrupt

  hipMemsetAsync(wsb, 0, 16384, stream);
  k_lnstats<<<3072, 256, 0, stream>>>(q, k, v, mu_rstd);
  k_splitW<<<dim3(8,8,2), 256, 0, stream>>>(W_in, W_out, Wth, Wtl, Woth, Wotl);
  k_projmm<<<dim3(64,4,3), 256, 0, stream>>>(q, k, v, ln_g, ln_b, Wth, Wtl,
                                             mu_rstd, fqh, fql, fkh, fkl, fvA,
                                             qgs, kgs);
  k_vT<<<dim3(16,32), 256, 0, stream>>>(fvA, fvTh, fvTl);
  k_nu<<<32, 256, 0, stream>>>(fkh, fkl, nuA, Sarr);
  k_rows<<<8192, 256, 0, stream>>>(fqh, fql, fkh, fkl, nuA,
                                   inv_na_q, muqA, tqA, inv_na_k, skA);
  k_wp<<<1, 256, 0, stream>>>(qgs, kgs, wp_W1, wp_b1, wp_lg, wp_lb,
                              wp_W2, wp_b2, wp_W3, wp_b3, wtemp, wp_out);
  k_passA<<<1024, 256, 0, stream>>>(fqh, fql, fkh, fkl,
                                    inv_na_q, muqA, tqA, inv_na_k, skA, Sarr,
                                    rs_cos, rs_cov, rs_marg,
                                    mxcos, mncos, mxcov, mncov, gacc);
  k_rowfin<<<128, 256, 0, stream>>>(rs_cos, rs_cov, rs_marg, var_row, racc);
  k_final<<<1, 64, 0, stream>>>(gacc, racc, wp_out, coef);
  k_pv<<<1024, 256, 0, stream>>>(fqh, fql, fkh, fkl, fvTh, fvTl,
                                 inv_na_q, muqA, tqA, inv_na_k, skA, Sarr,
                                 var_row, mxcos, mncos, mxcov, mncov, coef,
                                 ohh, ohl);
  k_outmm<<<dim3(64,4), 256, 0, stream>>>(ohh, ohl, Woth, Wotl, b_out, out);
}

// Round 9
// 320.046 us; speedup vs baseline: 1.6808x; 1.2011x over previous
//
#include <hip/hip_runtime.h>
#include <math.h>

#define NH    8
#define NQB   4
#define NPAIR 32
#define NTOK  1024
#define DH    64
#define DIMX  512
#define NROWS (NPAIR*NTOK)

typedef __attribute__((ext_vector_type(8))) short short8;
typedef _Float16 half8 __attribute__((ext_vector_type(8)));
typedef __attribute__((ext_vector_type(4))) float f32x4;

__device__ __forceinline__ unsigned short f2bf(float x){
  unsigned u = __float_as_uint(x);
  u += 0x7fffu + ((u>>16)&1u);
  return (unsigned short)(u>>16);
}
__device__ __forceinline__ float bf2f(unsigned short h){
  return __uint_as_float(((unsigned)h)<<16);
}
__device__ __forceinline__ unsigned short f2h(float x){
  union{ _Float16 f; unsigned short u; } c; c.f = (_Float16)x; return c.u;
}
__device__ __forceinline__ float h2f(unsigned short u){
  union{ _Float16 f; unsigned short u; } c; c.u = u; return (float)c.f;
}
__device__ __forceinline__ f32x4 mfma16(short8 a, short8 b, f32x4 c){
  return __builtin_amdgcn_mfma_f32_16x16x32_bf16(a,b,c,0,0,0);
}
__device__ __forceinline__ f32x4 mfma16f(half8 a, half8 b, f32x4 c){
  return __builtin_amdgcn_mfma_f32_16x16x32_f16(a,b,c,0,0,0);
}
// async global->LDS DMA, 16B per lane; LDS dest = base + lane*16
__device__ __forceinline__ void dma16(const void* g, void* l){
  __builtin_amdgcn_global_load_lds(
      (const __attribute__((address_space(1))) void*)g,
      (__attribute__((address_space(3))) void*)l, 16, 0, 0);
}

// chunk layout for 512-col matrices: [rowgrp64][colgrp64][cq8][row64][8]
__device__ __forceinline__ size_t cidx(int r, int c){
  return ((((size_t)((r>>6)*8 + (c>>6)))*8 + ((c&63)>>3))*64 + (r&63))*8 + (c&7);
}
// K layout: FK[p][kc][dq][k64][8]
__device__ __forceinline__ size_t kidx(int p, int key, int dh){
  return ((((size_t)(p*16 + (key>>6)))*8 + (dh>>3))*64 + (key&63))*8 + (dh&7);
}

// ------------------------------------------------- per-token LN statistics

__global__ __launch_bounds__(256) void k_lnstats(const float* __restrict__ q,
    const float* __restrict__ k, const float* __restrict__ v,
    float* __restrict__ mu_rstd){
  int wid = threadIdx.x >> 6, lane = threadIdx.x & 63;
  int tok = blockIdx.x*4 + wid;            // 0..12287
  const float* src = (tok < 4096) ? q : ((tok < 8192) ? k : v);
  int t = tok & 4095;
  const float4* p4 = (const float4*)(src + (size_t)t*DIMX) + lane*2;
  float4 a = p4[0], b = p4[1];
  float s  = a.x+a.y+a.z+a.w + b.x+b.y+b.z+b.w;
  float ss = a.x*a.x+a.y*a.y+a.z*a.z+a.w*a.w
           + b.x*b.x+b.y*b.y+b.z*b.z+b.w*b.w;
  #pragma unroll
  for (int off=32; off; off>>=1){ s += __shfl_down(s,off); ss += __shfl_down(ss,off); }
  if (lane==0){
    float mu = s*(1.0f/512.0f);
    float var = ss*(1.0f/512.0f) - mu*mu;
    mu_rstd[tok*2+0] = mu;
    mu_rstd[tok*2+1] = 1.0f/sqrtf(var + 1e-5f);
  }
}

// ------- transpose + hi/lo split of W_in and W_out -> chunk layout bf16

__global__ __launch_bounds__(256) void k_splitW(const float* __restrict__ Wa,
    const float* __restrict__ Wb,
    unsigned short* __restrict__ Wth, unsigned short* __restrict__ Wtl,
    unsigned short* __restrict__ Woth, unsigned short* __restrict__ Wotl){
  __shared__ float tile[64][65];
  int z = blockIdx.z;
  const float* W = z ? Wb : Wa;
  unsigned short* oh_ = z ? Woth : Wth;
  unsigned short* ol_ = z ? Wotl : Wtl;
  int kb = blockIdx.x, nb = blockIdx.y, tid = threadIdx.x;
  #pragma unroll
  for (int it=0; it<4; ++it){
    int idx = tid + 256*it;          // 0..1023
    int kr = idx>>4, c4 = idx&15;
    float4 vv = *(const float4*)(W + (size_t)(kb*64+kr)*DIMX + nb*64 + c4*4);
    tile[c4*4+0][kr]=vv.x; tile[c4*4+1][kr]=vv.y; tile[c4*4+2][kr]=vv.z; tile[c4*4+3][kr]=vv.w;
  }
  __syncthreads();
  #pragma unroll
  for (int it=0; it<4; ++it){
    int idx = tid + 256*it;
    int n = idx>>4, k4 = idx&15;
    size_t base = cidx(nb*64+n, kb*64+k4*4);
    ushort4 hv, lv;
    { float xx=tile[n][k4*4+0]; unsigned short hh=f2bf(xx); hv.x=hh; lv.x=f2bf(xx-bf2f(hh)); }
    { float xx=tile[n][k4*4+1]; unsigned short hh=f2bf(xx); hv.y=hh; lv.y=f2bf(xx-bf2f(hh)); }
    { float xx=tile[n][k4*4+2]; unsigned short hh=f2bf(xx); hv.z=hh; lv.z=f2bf(xx-bf2f(hh)); }
    { float xx=tile[n][k4*4+3]; unsigned short hh=f2bf(xx); hv.w=hh; lv.w=f2bf(xx-bf2f(hh)); }
    *(ushort4*)(oh_+base) = hv;
    *(ushort4*)(ol_+base) = lv;
  }
}

// --------------- LN + projection GEMM via split-bf16 MFMA (q, k, v by z)
// W fragments from LDS (DMA-staged chunk layout)

__global__ __launch_bounds__(256) void k_projmm(
    const float* __restrict__ q, const float* __restrict__ k, const float* __restrict__ v,
    const float* __restrict__ g, const float* __restrict__ bln,
    const unsigned short* __restrict__ Wth, const unsigned short* __restrict__ Wtl,
    const float* __restrict__ mu_rstd,
    unsigned short* __restrict__ fqh, unsigned short* __restrict__ fql,
    unsigned short* __restrict__ fkh, unsigned short* __restrict__ fkl,
    float* __restrict__ fv,
    double* __restrict__ qgs, double* __restrict__ kgs){
  __shared__ __align__(16) unsigned short Ahs[64*72];
  __shared__ __align__(16) unsigned short Als[64*72];
  __shared__ __align__(16) unsigned short WhL[2][4096];
  __shared__ __align__(16) unsigned short WlL[2][4096];
  __shared__ float scrc[4][128];
  int z = blockIdx.z;
  const float* x = (z==0) ? q : ((z==1) ? k : v);
  int mb = blockIdx.x, nb = blockIdx.y;
  int tid = threadIdx.x, w = tid>>6, l = tid&63, lm = l&15, qd = l>>4;
  int rbase = (w&1)*32;
  int tile = w>>1;
  int cbase = nb*128 + tile*64;
  scrc[tid>>7][tid&127] = 0.f;
  scrc[2+(tid>>7)][tid&127] = 0.f;
  f32x4 acc[2][4];
  #pragma unroll
  for (int mt=0;mt<2;++mt)
    #pragma unroll
    for (int nt=0;nt<4;++nt) acc[mt][nt] = (f32x4){0.f,0.f,0.f,0.f};
  for (int kc8 = 0; kc8 < 8; ++kc8){
    float4 xv[4]; float mus[4], rss[4]; float4 gv[4], bv[4]; int rr[4], kk4[4];
    #pragma unroll
    for (int it=0; it<4; ++it){
      int idx = tid + 256*it;          // 0..1023
      int r = idx>>4, k4 = idx&15;
      rr[it]=r; kk4[it]=k4;
      int tokg = z*4096 + mb*64 + r;
      mus[it] = mu_rstd[tokg*2+0]; rss[it] = mu_rstd[tokg*2+1];
      xv[it] = *(const float4*)(x + (size_t)(mb*64+r)*DIMX + kc8*64 + k4*4);
      gv[it] = *(const float4*)(g   + kc8*64 + k4*4);
      bv[it] = *(const float4*)(bln + kc8*64 + k4*4);
    }
    __syncthreads();                   // prev chunk consumed
    {  // wave w stages W chunk: tile w>>1, hi/lo w&1
      int st = w>>1, hl = w&1;
      const unsigned short* src = (hl ? Wtl : Wth)
          + ((size_t)((nb*2+st)*8 + kc8))*4096;
      unsigned short* dst = hl ? WlL[st] : WhL[st];
      #pragma unroll
      for (int j=0;j<8;++j) dma16(src + j*512 + l*8, dst + j*512);
    }
    #pragma unroll
    for (int it=0; it<4; ++it){
      float y0 = (xv[it].x-mus[it])*rss[it]*gv[it].x + bv[it].x;
      float y1 = (xv[it].y-mus[it])*rss[it]*gv[it].y + bv[it].y;
      float y2 = (xv[it].z-mus[it])*rss[it]*gv[it].z + bv[it].z;
      float y3 = (xv[it].w-mus[it])*rss[it]*gv[it].w + bv[it].w;
      ushort4 hv, lv;
      { unsigned short hh=f2bf(y0); hv.x=hh; lv.x=f2bf(y0-bf2f(hh)); }
      { unsigned short hh=f2bf(y1); hv.y=hh; lv.y=f2bf(y1-bf2f(hh)); }
      { unsigned short hh=f2bf(y2); hv.z=hh; lv.z=f2bf(y2-bf2f(hh)); }
      { unsigned short hh=f2bf(y3); hv.w=hh; lv.w=f2bf(y3-bf2f(hh)); }
      *(ushort4*)(Ahs + rr[it]*72 + kk4[it]*4) = hv;
      *(ushort4*)(Als + rr[it]*72 + kk4[it]*4) = lv;
    }
    __syncthreads();                   // staging + DMA visible
    #pragma unroll
    for (int kch=0; kch<2; ++kch){
      short8 a_h[2], a_l[2];
      #pragma unroll
      for (int mt=0;mt<2;++mt){
        a_h[mt] = *(const short8*)(Ahs + (rbase+mt*16+lm)*72 + kch*32 + qd*8);
        a_l[mt] = *(const short8*)(Als + (rbase+mt*16+lm)*72 + kch*32 + qd*8);
      }
      #pragma unroll
      for (int nt=0;nt<4;++nt){
        int off = ((kch*4+qd)*64 + nt*16+lm)*8;
        short8 bh = *(const short8*)(WhL[tile] + off);
        short8 bl = *(const short8*)(WlL[tile] + off);
        #pragma unroll
        for (int mt=0;mt<2;++mt){
          acc[mt][nt] = mfma16(a_h[mt], bh, acc[mt][nt]);
          acc[mt][nt] = mfma16(a_h[mt], bl, acc[mt][nt]);
          acc[mt][nt] = mfma16(a_l[mt], bh, acc[mt][nt]);
        }
      }
    }
  }
  int head = cbase >> 6;
  if (z < 2){
    float csum[4] = {0.f,0.f,0.f,0.f};
    #pragma unroll
    for (int mt=0;mt<2;++mt){
      #pragma unroll
      for (int nt=0;nt<4;++nt){
        #pragma unroll
        for (int i=0;i<4;++i){
          float val = acc[mt][nt][i];
          csum[nt] += val;
          int tglob = mb*64 + rbase + mt*16 + qd*4 + i;
          int qb = tglob>>10, n = tglob&1023;
          int p = head*4 + qb;
          int d = nt*16 + lm;
          unsigned short hh = f2bf(val);
          unsigned short ll = f2bf(val - bf2f(hh));
          if (z==0){
            size_t ix = ((size_t)(p*NTOK+n))*DH + d;
            fqh[ix] = hh; fql[ix] = ll;
          } else {
            size_t ix = kidx(p, n, d);
            fkh[ix] = hh; fkl[ix] = ll;
          }
        }
      }
    }
    #pragma unroll
    for (int m=16;m<64;m<<=1){
      #pragma unroll
      for (int nt=0;nt<4;++nt) csum[nt] += __shfl_xor(csum[nt], m);
    }
    if (qd==0){
      #pragma unroll
      for (int nt=0;nt<4;++nt) scrc[w][tile*64 + nt*16 + lm] = csum[nt];
    }
    __syncthreads();
    if (tid < 128){
      float s = scrc[0][tid]+scrc[1][tid]+scrc[2][tid]+scrc[3][tid];
      double* dst = (z==0) ? qgs : kgs;
      atomicAdd(&dst[nb*128 + tid], (double)s);
    }
  } else {
    #pragma unroll
    for (int mt=0;mt<2;++mt){
      #pragma unroll
      for (int nt=0;nt<4;++nt){
        #pragma unroll
        for (int i=0;i<4;++i){
          int tglob = mb*64 + rbase + mt*16 + qd*4 + i;
          int qb = tglob>>10, n = tglob&1023;
          int p = head*4 + qb;
          int d = nt*16 + lm;
          fv[((size_t)(p*NTOK+n))*DH + d] = acc[mt][nt][i];
        }
      }
    }
  }
}

// ------- transpose fv -> fvT (fp16 hi/lo, chunk layout [p][kc][kq][d][8])

__global__ __launch_bounds__(256) void k_vT(const float* __restrict__ fv,
    unsigned short* __restrict__ fvTh, unsigned short* __restrict__ fvTl){
  __shared__ float tile[64][65];
  int mc = blockIdx.x, p = blockIdx.y, tid = threadIdx.x;
  #pragma unroll
  for (int it=0; it<4; ++it){
    int idx = tid + 256*it;
    int m = idx>>4, d4 = idx&15;
    float4 vv = *(const float4*)(fv + ((size_t)(p*NTOK + mc*64 + m)*DH + d4*4));
    tile[d4*4+0][m]=vv.x; tile[d4*4+1][m]=vv.y; tile[d4*4+2][m]=vv.z; tile[d4*4+3][m]=vv.w;
  }
  __syncthreads();
  #pragma unroll
  for (int it=0; it<2; ++it){
    int idx = tid + 256*it;       // 0..511
    int d = idx>>3, seg = idx&7;  // keys seg*8..seg*8+8
    size_t base = ((((size_t)(p*16+mc))*8 + seg)*64 + d)*8;
    ushort4 h0,h1,l0,l1;
    { float xx=tile[d][seg*8+0]; unsigned short hh=f2h(xx); h0.x=hh; l0.x=f2h(xx-h2f(hh)); }
    { float xx=tile[d][seg*8+1]; unsigned short hh=f2h(xx); h0.y=hh; l0.y=f2h(xx-h2f(hh)); }
    { float xx=tile[d][seg*8+2]; unsigned short hh=f2h(xx); h0.z=hh; l0.z=f2h(xx-h2f(hh)); }
    { float xx=tile[d][seg*8+3]; unsigned short hh=f2h(xx); h0.w=hh; l0.w=f2h(xx-h2f(hh)); }
    { float xx=tile[d][seg*8+4]; unsigned short hh=f2h(xx); h1.x=hh; l1.x=f2h(xx-h2f(hh)); }
    { float xx=tile[d][seg*8+5]; unsigned short hh=f2h(xx); h1.y=hh; l1.y=f2h(xx-h2f(hh)); }
    { float xx=tile[d][seg*8+6]; unsigned short hh=f2h(xx); h1.z=hh; l1.z=f2h(xx-h2f(hh)); }
    { float xx=tile[d][seg*8+7]; unsigned short hh=f2h(xx); h1.w=hh; l1.w=f2h(xx-h2f(hh)); }
    *(ushort4*)(fvTh+base)   = h0;
    *(ushort4*)(fvTh+base+4) = h1;
    *(ushort4*)(fvTl+base)   = l0;
    *(ushort4*)(fvTl+base+4) = l1;
  }
}

// -------------------------------------------- nu (col-means of f_k) and S

__global__ __launch_bounds__(256) void k_nu(const unsigned short* __restrict__ fkh,
    const unsigned short* __restrict__ fkl,
    float* __restrict__ nuA, float* __restrict__ Sarr){
  __shared__ float red[4][64];
  int p = blockIdx.x, tid = threadIdx.x;
  int td = tid & 63, tm = tid >> 6;
  float s = 0.f;
  for (int m = tm; m < NTOK; m += 4){
    size_t ix = kidx(p, m, td);
    s += bf2f(fkh[ix]) + bf2f(fkl[ix]);
  }
  red[tm][td] = s;
  __syncthreads();
  if (tid < 64){
    float tot = red[0][tid]+red[1][tid]+red[2][tid]+red[3][tid];
    float nuv = tot * (1.0f/1024.0f);
    nuA[p*DH+tid] = nuv;
    float sv = nuv;
    #pragma unroll
    for (int off=32; off; off>>=1) sv += __shfl_down(sv, off);
    if (tid==0) Sarr[p] = sv;
  }
}

// --------------------------------------- per-row scalars for f_q and f_k

__global__ __launch_bounds__(256) void k_rows(
    const unsigned short* __restrict__ fqh, const unsigned short* __restrict__ fql,
    const unsigned short* __restrict__ fkh, const unsigned short* __restrict__ fkl,
    const float* __restrict__ nuA,
    float* __restrict__ inv_na_q, float* __restrict__ muqA, float* __restrict__ tqA,
    float* __restrict__ inv_na_k, float* __restrict__ skA){
  int wid = threadIdx.x >> 6, lane = threadIdx.x & 63;
  int row = blockIdx.x*4 + wid;            // < 32768
  int p = row >> 10;
  int key = row & 1023;
  size_t ix = (size_t)row*DH + lane;
  float xq = bf2f(fqh[ix]) + bf2f(fql[ix]);
  float nv = nuA[p*DH + lane];
  float s = xq, ss = xq*xq, sd = xq*nv;
  #pragma unroll
  for (int off=32; off; off>>=1){
    s += __shfl_down(s,off); ss += __shfl_down(ss,off); sd += __shfl_down(sd,off);
  }
  if (lane==0){
    float nrm = sqrtf(ss);
    inv_na_q[row] = 1.0f/(nrm+1e-8f);
    muqA[row] = s*(1.0f/64.0f);
    tqA[row] = sd;
  }
  size_t ixk = kidx(p, key, lane);
  float xk = bf2f(fkh[ixk]) + bf2f(fkl[ixk]);
  float s2 = xk, ss2 = xk*xk;
  #pragma unroll
  for (int off=32; off; off>>=1){
    s2 += __shfl_down(s2,off); ss2 += __shfl_down(ss2,off);
  }
  if (lane==0){
    float nrm = sqrtf(ss2);
    inv_na_k[row] = 1.0f/(nrm+1e-8f);
    skA[row] = s2;
  }
}

// ------------------------------------------------- weight predictor (tiny)

__global__ __launch_bounds__(256) void k_wp(const double* __restrict__ qgs,
    const double* __restrict__ kgs,
    const float* __restrict__ W1, const float* __restrict__ b1,
    const float* __restrict__ lgv, const float* __restrict__ lbv,
    const float* __restrict__ W2, const float* __restrict__ b2,
    const float* __restrict__ W3, const float* __restrict__ b3,
    const float* __restrict__ wtemp, float* __restrict__ wp_out){
  __shared__ float feats[8][128];
  __shared__ float h1[8][64];
  __shared__ float h2s[8][32];
  __shared__ float lgt[8][3];
  __shared__ float mv[8][2];
  int tid = threadIdx.x;
  for (int idx = tid; idx < 1024; idx += 256){
    int h = idx >> 7, i = idx & 127;
    double vv = (i < 64) ? qgs[h*64+i] : kgs[h*64+(i-64)];
    feats[h][i] = (float)(vv * (1.0/4096.0));
  }
  __syncthreads();
  for (int idx = tid; idx < 512; idx += 256){
    int h = idx >> 6, j = idx & 63;
    float s = b1[j];
    for (int i = 0; i < 128; ++i) s += feats[h][i]*W1[i*64+j];
    h1[h][j] = s;
  }
  __syncthreads();
  if (tid < 8){
    float s=0.f, ss=0.f;
    for (int j=0;j<64;++j){ float vv=h1[tid][j]; s+=vv; ss+=vv*vv; }
    float mu = s*(1.0f/64.0f);
    float var = ss*(1.0f/64.0f)-mu*mu;
    mv[tid][0]=mu; mv[tid][1]=1.0f/sqrtf(var+1e-5f);
  }
  __syncthreads();
  for (int idx = tid; idx < 512; idx += 256){
    int h = idx>>6, j = idx&63;
    float vv = (h1[h][j]-mv[h][0])*mv[h][1]*lgv[j] + lbv[j];
    h1[h][j] = fmaxf(vv, 0.f);
  }
  __syncthreads();
  {
    int h = tid >> 5, j = tid & 31;
    float s = b2[j];
    for (int i=0;i<64;++i) s += h1[h][i]*W2[i*32+j];
    h2s[h][j] = fmaxf(s, 0.f);
  }
  __syncthreads();
  if (tid < 24){
    int h = tid/3, j = tid - h*3;
    float s = b3[j];
    for (int i=0;i<32;++i) s += h2s[h][i]*W3[i*3+j];
    lgt[h][j] = s;
  }
  __syncthreads();
  if (tid < 8){
    int h = tid;
    float z0=lgt[h][0], z1=lgt[h][1], z2=lgt[h][2];
    float m = fmaxf(z0,fmaxf(z1,z2));
    float e0=expf(z0-m), e1=expf(z1-m), e2=expf(z2-m);
    float inv = 1.0f/(e0+e1+e2);
    float l0=e0*inv, l1=e1*inv, l2=e2*inv;
    float wt = fminf(fmaxf(wtemp[0], 0.1f), 20.0f);
    float y0=l0/wt, y1=l1/wt, y2=l2/wt;
    float m2 = fmaxf(y0,fmaxf(y1,y2));
    float f0=expf(y0-m2), f1=expf(y1-m2), f2=expf(y2-m2);
    float inv2 = 1.0f/(f0+f1+f2);
    float w0=f0*inv2, w1=f1*inv2, w2=f2*inv2;
    w0 = fminf(fmaxf(w0,0.05f),0.8f);
    w1 = fminf(fmaxf(w1,0.05f),0.8f);
    w2 = fminf(fmaxf(w2,0.05f),0.8f);
    float isum = 1.0f/(w0+w1+w2);
    wp_out[h*3+0]=w0*isum; wp_out[h*3+1]=w1*isum; wp_out[h*3+2]=w2*isum;
  }
}

// ------------- pass A (MFMA): K staged via global_load_lds; QK + stats.

__global__ __launch_bounds__(256) void k_passA(
    const unsigned short* __restrict__ fqh, const unsigned short* __restrict__ fql,
    const unsigned short* __restrict__ fkh, const unsigned short* __restrict__ fkl,
    const float* __restrict__ inv_na_q, const float* __restrict__ muqA,
    const float* __restrict__ tqA,
    const float* __restrict__ inv_na_k, const float* __restrict__ skA,
    const float* __restrict__ Sarr,
    float* __restrict__ rs_cos, float* __restrict__ rs_cov, float* __restrict__ rs_marg,
    float* __restrict__ mxcosA, float* __restrict__ mncosA,
    float* __restrict__ mxcovA, float* __restrict__ mncovA,
    double* __restrict__ gacc){
  __shared__ __align__(16) unsigned short Kh[4096];
  __shared__ __align__(16) unsigned short Kl[4096];
  __shared__ float redbuf[4][16][7];
  __shared__ double wredS[4][3];
  int b = blockIdx.x;
  int p = ((b&7)<<2) | ((b>>3)&3);   // XCD swizzle
  int s = b>>5;                      // 0..31
  int n0 = s*32;
  int tid = threadIdx.x, w = tid>>6, l = tid&63;
  int lm = l&15, q = l>>4;
  int rt = w&1, cw = w>>1;
  int nw = n0 + rt*16;
  float Sp = Sarr[p];
  const float inv8 = (float)(1.0/(8.0+1e-6));
  float ia[4], m8[4], t8[4];
  #pragma unroll
  for (int i=0;i<4;++i){
    int rg = p*NTOK + nw + q*4 + i;
    float mq = muqA[rg];
    ia[i] = inv_na_q[rg];
    m8[i] = mq*inv8;
    t8[i] = (tqA[rg] - mq*Sp)*inv8;
  }
  const short8* aqh = (const short8*)(fqh + (size_t)(p*NTOK + nw + lm)*DH);
  const short8* aql = (const short8*)(fql + (size_t)(p*NTOK + nw + lm)*DH);
  short8 ah0 = aqh[q], ah1 = aqh[4+q], al0 = aql[q], al1 = aql[4+q];
  const unsigned short* gKh = fkh + (size_t)p*16*4096;
  const unsigned short* gKl = fkl + (size_t)p*16*4096;
  const float* cAg = inv_na_k + p*NTOK;
  const float* cSg = skA + p*NTOK;
  float sc2=0.f, sv2=0.f, scv=0.f;
  float pc[4]={0,0,0,0}, pv_[4]={0,0,0,0}, pm[4]={0,0,0,0};
  float xc[4], nc[4], xv[4], nv[4];
  #pragma unroll
  for (int i=0;i<4;++i){ xc[i]=-1e30f; nc[i]=1e30f; xv[i]=-1e30f; nv[i]=1e30f; }
  for (int cc=0; cc<16; ++cc){
    __syncthreads();                 // previous chunk fully consumed
    {
      int r = w*2;
      const unsigned short* cb = gKh + cc*4096;
      dma16(cb + (r  )*512 + l*8, &Kh[(r  )*512]);
      dma16(cb + (r+1)*512 + l*8, &Kh[(r+1)*512]);
      cb = gKl + cc*4096;
      dma16(cb + (r  )*512 + l*8, &Kl[(r  )*512]);
      dma16(cb + (r+1)*512 + l*8, &Kl[(r+1)*512]);
    }
    __syncthreads();                 // staged data visible
    #pragma unroll
    for (int t2=0; t2<2; ++t2){
      int c16 = cw*2 + t2;
      short8 kh0 = *(const short8*)&Kh[((q  )*64 + c16*16+lm)*8];
      short8 kh1 = *(const short8*)&Kh[((q+4)*64 + c16*16+lm)*8];
      short8 kl0 = *(const short8*)&Kl[((q  )*64 + c16*16+lm)*8];
      short8 kl1 = *(const short8*)&Kl[((q+4)*64 + c16*16+lm)*8];
      f32x4 acc = {0.f,0.f,0.f,0.f};
      acc = mfma16(ah0,kh0,acc); acc = mfma16(ah1,kh1,acc);
      acc = mfma16(al0,kh0,acc); acc = mfma16(al1,kh1,acc);
      acc = mfma16(ah0,kl0,acc); acc = mfma16(ah1,kl1,acc);
      int colg = cc*64 + c16*16 + lm;
      float ca = cAg[colg], cs = cSg[colg];
      #pragma unroll
      for (int i=0;i<4;++i){
        float dot = acc[i];
        float cosv = fminf(fmaxf(dot*ia[i]*ca,-0.99f),0.99f);
        float cov  = fmaf(-m8[i], cs, fmaf(dot, inv8, -t8[i]));
        float marg = fmaxf(0.01f - cosv, 0.f);
        sc2 = fmaf(cosv,cosv,sc2); sv2 = fmaf(cov,cov,sv2); scv = fmaf(cosv,cov,scv);
        pc[i]+=cosv; pv_[i]+=cov; pm[i]+=marg;
        xc[i]=fmaxf(xc[i],cosv); nc[i]=fminf(nc[i],cosv);
        xv[i]=fmaxf(xv[i],cov);  nv[i]=fminf(nv[i],cov);
      }
    }
  }
  #pragma unroll
  for (int m=1;m<16;m<<=1){
    #pragma unroll
    for (int i=0;i<4;++i){
      pc[i]+=__shfl_xor(pc[i],m); pv_[i]+=__shfl_xor(pv_[i],m); pm[i]+=__shfl_xor(pm[i],m);
      xc[i]=fmaxf(xc[i],__shfl_xor(xc[i],m)); nc[i]=fminf(nc[i],__shfl_xor(nc[i],m));
      xv[i]=fmaxf(xv[i],__shfl_xor(xv[i],m)); nv[i]=fminf(nv[i],__shfl_xor(nv[i],m));
    }
  }
  if (lm==0){
    #pragma unroll
    for (int i=0;i<4;++i){
      int r16 = q*4+i;
      redbuf[w][r16][0]=pc[i]; redbuf[w][r16][1]=pv_[i]; redbuf[w][r16][2]=pm[i];
      redbuf[w][r16][3]=xc[i]; redbuf[w][r16][4]=nc[i];
      redbuf[w][r16][5]=xv[i]; redbuf[w][r16][6]=nv[i];
    }
  }
  double vals[3] = {(double)sc2,(double)sv2,(double)scv};
  #pragma unroll
  for (int c2=0;c2<3;++c2){
    double vv = vals[c2];
    #pragma unroll
    for (int off=32; off; off>>=1) vv += __shfl_down(vv, off);
    if (l==0) wredS[w][c2] = vv;
  }
  __syncthreads();
  if (tid < 32){
    int rt2 = tid>>4, r16 = tid&15;
    int w0 = rt2, w1 = rt2+2;
    float sc = redbuf[w0][r16][0]+redbuf[w1][r16][0];
    float sv = redbuf[w0][r16][1]+redbuf[w1][r16][1];
    float sm = redbuf[w0][r16][2]+redbuf[w1][r16][2];
    float mxc = fmaxf(redbuf[w0][r16][3],redbuf[w1][r16][3]);
    float mnc = fminf(redbuf[w0][r16][4],redbuf[w1][r16][4]);
    float mxv = fmaxf(redbuf[w0][r16][5],redbuf[w1][r16][5]);
    float mnv = fminf(redbuf[w0][r16][6],redbuf[w1][r16][6]);
    int row = p*NTOK + n0 + tid;
    rs_cos[row]=sc; rs_cov[row]=sv; rs_marg[row]=sm;
    mxcosA[row]=mxc; mncosA[row]=mnc; mxcovA[row]=mxv; mncovA[row]=mnv;
  }
  if (tid == 0){
    int h = p >> 2;
    #pragma unroll
    for (int c2=0;c2<3;++c2){
      double t = wredS[0][c2]+wredS[1][c2]+wredS[2][c2]+wredS[3][c2];
      atomicAdd(&gacc[h*3+c2], t);
    }
  }
}

// ---------------------- row finish: var_row + row-sum-derived moments

__global__ __launch_bounds__(256) void k_rowfin(const float* __restrict__ rs_cos,
    const float* __restrict__ rs_cov, const float* __restrict__ rs_marg,
    float* __restrict__ var_row, double* __restrict__ racc){
  __shared__ double wredS[4][6];
  int row = blockIdx.x*256 + threadIdx.x;
  int p = row >> 10; int h = p >> 2;
  float vr = rs_marg[row] * (1.0f/1024.0f);
  var_row[row] = vr;
  double dv = (double)vr;
  double rc = (double)rs_cos[row], rv = (double)rs_cov[row];
  double vals[6];
  vals[0] = 1024.0*dv;
  vals[1] = 1024.0*dv*dv;
  vals[2] = dv*rc;
  vals[3] = dv*rv;
  vals[4] = rc;
  vals[5] = rv;
  int lane = threadIdx.x & 63, wid = threadIdx.x >> 6;
  #pragma unroll
  for (int c2 = 0; c2 < 6; ++c2){
    double vv = vals[c2];
    #pragma unroll
    for (int off=32; off; off>>=1) vv += __shfl_down(vv, off);
    if (lane==0) wredS[wid][c2] = vv;
  }
  __syncthreads();
  if (threadIdx.x == 0){
    #pragma unroll
    for (int c2 = 0; c2 < 6; ++c2){
      double t = wredS[0][c2]+wredS[1][c2]+wredS[2][c2]+wredS[3][c2];
      atomicAdd(&racc[h*6+c2], t);
    }
  }
}

// ------------------------------------- finalize scalars -> d2 coefficients

__global__ void k_final(const double* __restrict__ gacc, const double* __restrict__ racc,
                        const float* __restrict__ wp_out, float* __restrict__ coef){
  if (threadIdx.x != 0) return;
  const double N = 33554432.0;
  double Sc1=0,Sc2=0,Sv1=0,Sv2=0,Sr1=0,Sr2=0;
  for (int h=0;h<8;++h){
    Sc2+=gacc[h*3+0]; Sv2+=gacc[h*3+1];
    Sr1+=racc[h*6+0]; Sr2+=racc[h*6+1];
    Sc1+=racc[h*6+4]; Sv1+=racc[h*6+5];
  }
  double cvar = (Sc2 - Sc1*Sc1/N)/(N-1.0);
  double cn = sqrt(fmax(cvar,0.0)) + 1e-6;
  double cscale = (cn < 1e-4) ? 0.1 : 1.0;
  double vraw = (Sv2 - Sv1*Sv1/N)/(N-1.0);
  double sraw = sqrt(fmax(vraw,0.0));
  double basev = 0.001/1024.0;
  double regv = (sraw < 1e-6) ? basev*10.0 : basev;
  double covn = regv*sraw + 1e-6;
  double vvar = (Sr2 - Sr1*Sr1/N)/(N-1.0);
  double vn = sqrt(fmax(vvar,0.0)) + 1e-6;
  double ah[8], bh[8], chh[8];
  double Sd1=0.0, Sd2=0.0;
  for (int h=0;h<8;++h){
    double a = (double)wp_out[h*3+0]/cn*cscale;
    double b = (double)wp_out[h*3+1]*regv*0.5/covn;
    double c = (double)wp_out[h*3+2]*0.5/vn;
    ah[h]=a; bh[h]=b; chh[h]=c;
    Sd1 += a*racc[h*6+4] + b*racc[h*6+5] + c*racc[h*6+0];
    Sd2 += a*a*gacc[h*3+0] + b*b*gacc[h*3+1] + c*c*racc[h*6+1]
         + 2.0*(a*b*gacc[h*3+2] + a*c*racc[h*6+2] + b*c*racc[h*6+3]);
  }
  double dvar = (Sd2 - Sd1*Sd1/N)/(N-1.0);
  double dstd = sqrt(fmax(dvar,0.0));
  double temp = (dstd < 1e-6) ? 0.1 : 0.3 + dstd;
  double tcl = fmin(fmax(temp,0.1),5.0);
  double it = 1.0/tcl;
  for (int h=0;h<8;++h){
    coef[h*3+0] = (float)(ah[h]*it);
    coef[h*3+1] = (float)(bh[h]*it);
    coef[h*3+2] = (float)(chh[h]*it);
  }
}

// -------------------- pass C (MFMA): K/V staged via global_load_lds.
// oh written in chunk layout (cidx) for DMA staging in k_outmm.

__global__ __launch_bounds__(256) void k_pv(
    const unsigned short* __restrict__ fqh, const unsigned short* __restrict__ fql,
    const unsigned short* __restrict__ fkh, const unsigned short* __restrict__ fkl,
    const unsigned short* __restrict__ fvTh, const unsigned short* __restrict__ fvTl,
    const float* __restrict__ inv_na_q, const float* __restrict__ muqA,
    const float* __restrict__ tqA,
    const float* __restrict__ inv_na_k, const float* __restrict__ skA,
    const float* __restrict__ Sarr, const float* __restrict__ var_row,
    const float* __restrict__ mxcosA, const float* __restrict__ mncosA,
    const float* __restrict__ mxcovA, const float* __restrict__ mncovA,
    const float* __restrict__ coef,
    unsigned short* __restrict__ ohh, unsigned short* __restrict__ ohl){
  __shared__ __align__(16) unsigned short Kh[4096];
  __shared__ __align__(16) unsigned short Kl[4096];
  __shared__ __align__(16) unsigned short Vh[4096];
  __shared__ __align__(16) unsigned short Vl[4096];
  __shared__ __align__(16) unsigned short ph[32][72];
  __shared__ float denbuf[4][16];
  __shared__ float dnv[32];
  int b = blockIdx.x;
  int p = ((b&7)<<2) | ((b>>3)&3);   // XCD swizzle
  int s = b>>5;
  int n0 = s*32;
  int h = p>>2, qb = p&3;
  int tid = threadIdx.x, w = tid>>6, l = tid&63;
  int lm = l&15, q = l>>4;
  int rt = w&1, cw = w>>1;
  int nw = n0 + rt*16;
  float A = coef[h*3+0], B = coef[h*3+1], C = coef[h*3+2];
  float Sp = Sarr[p];
  const float inv8 = (float)(1.0/(8.0+1e-6));
  float B8 = B*inv8;
  float ia[4], bm[4], o2[4];
  #pragma unroll
  for (int i=0;i<4;++i){
    int rg = p*NTOK + nw + q*4 + i;
    float mq = muqA[rg];
    ia[i] = inv_na_q[rg];
    bm[i] = B8*mq;
    float tq2 = tqA[rg] - mq*Sp;
    float vr = var_row[rg];
    float Mh = fmaxf(A*mxcosA[rg],A*mncosA[rg]) + fmaxf(B*mxcovA[rg],B*mncovA[rg]) + C*vr;
    o2[i] = (C*vr - Mh) - B8*tq2;
  }
  const short8* aqh = (const short8*)(fqh + (size_t)(p*NTOK + nw + lm)*DH);
  const short8* aql = (const short8*)(fql + (size_t)(p*NTOK + nw + lm)*DH);
  short8 ah0 = aqh[q], ah1 = aqh[4+q], al0 = aql[q], al1 = aql[4+q];
  const unsigned short* gKh = fkh  + (size_t)p*16*4096;
  const unsigned short* gKl = fkl  + (size_t)p*16*4096;
  const unsigned short* gVh = fvTh + (size_t)p*16*4096;
  const unsigned short* gVl = fvTl + (size_t)p*16*4096;
  const float* cAg = inv_na_k + p*NTOK;
  const float* cSg = skA + p*NTOK;
  f32x4 o0 = {0.f,0.f,0.f,0.f}, o1 = {0.f,0.f,0.f,0.f};
  float den[4] = {0.f,0.f,0.f,0.f};
  for (int cc = 0; cc < 16; ++cc){
    __syncthreads();                 // previous chunk (incl. PV reads) done
    {
      int r = w*2;
      const unsigned short* cb = gKh + cc*4096;
      dma16(cb + (r  )*512 + l*8, &Kh[(r  )*512]);
      dma16(cb + (r+1)*512 + l*8, &Kh[(r+1)*512]);
      cb = gKl + cc*4096;
      dma16(cb + (r  )*512 + l*8, &Kl[(r  )*512]);
      dma16(cb + (r+1)*512 + l*8, &Kl[(r+1)*512]);
      cb = gVh + cc*4096;
      dma16(cb + (r  )*512 + l*8, &Vh[(r  )*512]);
      dma16(cb + (r+1)*512 + l*8, &Vh[(r+1)*512]);
      cb = gVl + cc*4096;
      dma16(cb + (r  )*512 + l*8, &Vl[(r  )*512]);
      dma16(cb + (r+1)*512 + l*8, &Vl[(r+1)*512]);
    }
    __syncthreads();                 // staged data visible
    #pragma unroll
    for (int t2=0; t2<2; ++t2){
      int c16 = cw*2 + t2;
      short8 kh0 = *(const short8*)&Kh[((q  )*64 + c16*16+lm)*8];
      short8 kh1 = *(const short8*)&Kh[((q+4)*64 + c16*16+lm)*8];
      short8 kl0 = *(const short8*)&Kl[((q  )*64 + c16*16+lm)*8];
      short8 kl1 = *(const short8*)&Kl[((q+4)*64 + c16*16+lm)*8];
      f32x4 acc = {0.f,0.f,0.f,0.f};
      acc = mfma16(ah0,kh0,acc); acc = mfma16(ah1,kh1,acc);
      acc = mfma16(al0,kh0,acc); acc = mfma16(al1,kh1,acc);
      acc = mfma16(ah0,kl0,acc); acc = mfma16(ah1,kl1,acc);
      int colg = cc*64 + c16*16 + lm;
      float ca = cAg[colg], cs = cSg[colg];
      #pragma unroll
      for (int i=0;i<4;++i){
        float dot = acc[i];
        float cosv = fminf(fmaxf(dot*ia[i]*ca,-0.99f),0.99f);
        float arg = fmaf(A, cosv, fmaf(-bm[i], cs, fmaf(B8, dot, o2[i])));
        float e = __expf(arg);
        unsigned short us = f2h(e);
        ph[rt*16+q*4+i][c16*16+lm] = us;
        den[i] += h2f(us);
      }
    }
    __syncthreads();                 // P complete
    {
      half8 vh0 = *(const half8*)&Vh[((q  )*64 + w*16+lm)*8];
      half8 vh1 = *(const half8*)&Vh[((q+4)*64 + w*16+lm)*8];
      half8 vl0 = *(const half8*)&Vl[((q  )*64 + w*16+lm)*8];
      half8 vl1 = *(const half8*)&Vl[((q+4)*64 + w*16+lm)*8];
      half8 pb00 = *(const half8*)&ph[lm][q*8];
      half8 pb01 = *(const half8*)&ph[lm][32+q*8];
      half8 pb10 = *(const half8*)&ph[16+lm][q*8];
      half8 pb11 = *(const half8*)&ph[16+lm][32+q*8];
      o0 = mfma16f(vh0,pb00,o0); o0 = mfma16f(vl0,pb00,o0);
      o0 = mfma16f(vh1,pb01,o0); o0 = mfma16f(vl1,pb01,o0);
      o1 = mfma16f(vh0,pb10,o1); o1 = mfma16f(vl0,pb10,o1);
      o1 = mfma16f(vh1,pb11,o1); o1 = mfma16f(vl1,pb11,o1);
    }
  }
  #pragma unroll
  for (int m=1;m<16;m<<=1){
    #pragma unroll
    for (int i=0;i<4;++i) den[i] += __shfl_xor(den[i],m);
  }
  if (lm==0){
    #pragma unroll
    for (int i=0;i<4;++i) denbuf[w][q*4+i] = den[i];
  }
  __syncthreads();
  if (tid < 32){
    int rt2 = tid>>4, r16 = tid&15;
    dnv[tid] = 1.0f/(denbuf[rt2][r16] + denbuf[rt2+2][r16]);
  }
  __syncthreads();
  {
    float inv0 = dnv[lm];
    float inv1 = dnv[16+lm];
    int dcol = h*64 + w*16 + q*4;
    int row0 = qb*NTOK + n0 + lm;
    int row1 = row0 + 16;
    size_t b0i = cidx(row0, dcol);
    size_t b1i = cidx(row1, dcol);
    ushort4 h0,l0,h1,l1;
    { float xx=o0[0]*inv0; unsigned short hh=f2bf(xx); h0.x=hh; l0.x=f2bf(xx-bf2f(hh)); }
    { float xx=o0[1]*inv0; unsigned short hh=f2bf(xx); h0.y=hh; l0.y=f2bf(xx-bf2f(hh)); }
    { float xx=o0[2]*inv0; unsigned short hh=f2bf(xx); h0.z=hh; l0.z=f2bf(xx-bf2f(hh)); }
    { float xx=o0[3]*inv0; unsigned short hh=f2bf(xx); h0.w=hh; l0.w=f2bf(xx-bf2f(hh)); }
    { float xx=o1[0]*inv1; unsigned short hh=f2bf(xx); h1.x=hh; l1.x=f2bf(xx-bf2f(hh)); }
    { float xx=o1[1]*inv1; unsigned short hh=f2bf(xx); h1.y=hh; l1.y=f2bf(xx-bf2f(hh)); }
    { float xx=o1[2]*inv1; unsigned short hh=f2bf(xx); h1.z=hh; l1.z=f2bf(xx-bf2f(hh)); }
    { float xx=o1[3]*inv1; unsigned short hh=f2bf(xx); h1.w=hh; l1.w=f2bf(xx-bf2f(hh)); }
    *(ushort4*)(ohh+b0i)=h0; *(ushort4*)(ohl+b0i)=l0;
    *(ushort4*)(ohh+b1i)=h1; *(ushort4*)(ohl+b1i)=l1;
  }
}

// ----------------- output GEMM (MFMA): A and W staged via global_load_lds

__global__ __launch_bounds__(256) void k_outmm(
    const unsigned short* __restrict__ ohh, const unsigned short* __restrict__ ohl,
    const unsigned short* __restrict__ Woth, const unsigned short* __restrict__ Wotl,
    const float* __restrict__ bias, float* __restrict__ out){
  __shared__ __align__(16) unsigned short Ah[4096];
  __shared__ __align__(16) unsigned short Al[4096];
  __shared__ __align__(16) unsigned short W0h[4096];
  __shared__ __align__(16) unsigned short W0l[4096];
  __shared__ __align__(16) unsigned short W1h[4096];
  __shared__ __align__(16) unsigned short W1l[4096];
  int mb = blockIdx.x, nb = blockIdx.y;
  int tid = threadIdx.x, w = tid>>6, l = tid&63, lm = l&15, qd = l>>4;
  int rh = w&1, tile = w>>1;
  int cbase = nb*128 + tile*64;
  f32x4 acc[2][4];
  #pragma unroll
  for (int mt=0;mt<2;++mt)
    #pragma unroll
    for (int nt=0;nt<4;++nt) acc[mt][nt] = (f32x4){0.f,0.f,0.f,0.f};
  for (int kc8=0; kc8<8; ++kc8){
    __syncthreads();
    {
      const unsigned short* aSh = ohh  + ((size_t)(mb*8+kc8))*4096;
      const unsigned short* aSl = ohl  + ((size_t)(mb*8+kc8))*4096;
      const unsigned short* s0h = Woth + ((size_t)((nb*2  )*8+kc8))*4096;
      const unsigned short* s0l = Wotl + ((size_t)((nb*2  )*8+kc8))*4096;
      const unsigned short* s1h = Woth + ((size_t)((nb*2+1)*8+kc8))*4096;
      const unsigned short* s1l = Wotl + ((size_t)((nb*2+1)*8+kc8))*4096;
      if (w==0){
        #pragma unroll
        for (int j=0;j<8;++j) dma16(aSh + j*512 + l*8, &Ah[j*512]);
        #pragma unroll
        for (int j=0;j<4;++j) dma16(s1h + j*512 + l*8, &W1h[j*512]);
      } else if (w==1){
        #pragma unroll
        for (int j=0;j<8;++j) dma16(aSl + j*512 + l*8, &Al[j*512]);
        #pragma unroll
        for (int j=4;j<8;++j) dma16(s1h + j*512 + l*8, &W1h[j*512]);
      } else if (w==2){
        #pragma unroll
        for (int j=0;j<8;++j) dma16(s0h + j*512 + l*8, &W0h[j*512]);
        #pragma unroll
        for (int j=0;j<4;++j) dma16(s1l + j*512 + l*8, &W1l[j*512]);
      } else {
        #pragma unroll
        for (int j=0;j<8;++j) dma16(s0l + j*512 + l*8, &W0l[j*512]);
        #pragma unroll
        for (int j=4;j<8;++j) dma16(s1l + j*512 + l*8, &W1l[j*512]);
      }
    }
    __syncthreads();
    const unsigned short* Wh_ = tile ? W1h : W0h;
    const unsigned short* Wl_ = tile ? W1l : W0l;
    #pragma unroll
    for (int kch=0; kch<2; ++kch){
      short8 a_h[2], a_l[2];
      #pragma unroll
      for (int mt=0;mt<2;++mt){
        int off = ((kch*4+qd)*64 + rh*32 + mt*16 + lm)*8;
        a_h[mt] = *(const short8*)(Ah + off);
        a_l[mt] = *(const short8*)(Al + off);
      }
      #pragma unroll
      for (int nt=0;nt<4;++nt){
        int off = ((kch*4+qd)*64 + nt*16+lm)*8;
        short8 bh = *(const short8*)(Wh_ + off);
        short8 bl = *(const short8*)(Wl_ + off);
        #pragma unroll
        for (int mt=0;mt<2;++mt){
          acc[mt][nt] = mfma16(a_h[mt], bh, acc[mt][nt]);
          acc[mt][nt] = mfma16(a_h[mt], bl, acc[mt][nt]);
          acc[mt][nt] = mfma16(a_l[mt], bh, acc[mt][nt]);
        }
      }
    }
  }
  float bv[4];
  #pragma unroll
  for (int nt=0;nt<4;++nt) bv[nt] = bias[cbase+nt*16+lm];
  #pragma unroll
  for (int mt=0;mt<2;++mt){
    #pragma unroll
    for (int i=0;i<4;++i){
      int row = mb*64 + rh*32 + mt*16 + qd*4 + i;
      #pragma unroll
      for (int nt=0;nt<4;++nt){
        out[(size_t)row*DIMX + cbase + nt*16 + lm] = acc[mt][nt][i] + bv[nt];
      }
    }
  }
}

// ----------------------------------------------------------------- launch

extern "C" void kernel_launch(void* const* d_in, const int* in_sizes, int n_in,
                              void* d_out, int out_size, void* d_ws, size_t ws_size,
                              hipStream_t stream) {
  (void)in_sizes; (void)n_in; (void)out_size;
  const float* q     = (const float*)d_in[0];
  const float* k     = (const float*)d_in[1];
  const float* v     = (const float*)d_in[2];
  const float* ln_g  = (const float*)d_in[3];
  const float* ln_b  = (const float*)d_in[4];
  const float* W_in  = (const float*)d_in[5];
  const float* wp_W1 = (const float*)d_in[6];
  const float* wp_b1 = (const float*)d_in[7];
  const float* wp_lg = (const float*)d_in[8];
  const float* wp_lb = (const float*)d_in[9];
  const float* wp_W2 = (const float*)d_in[10];
  const float* wp_b2 = (const float*)d_in[11];
  const float* wp_W3 = (const float*)d_in[12];
  const float* wp_b3 = (const float*)d_in[13];
  const float* wtemp = (const float*)d_in[14];
  const float* W_out = (const float*)d_in[15];
  const float* b_out = (const float*)d_in[16];
  float* out = (float*)d_out;

  char* wsb = (char*)d_ws;
  double* gacc = (double*)wsb;            // 24 doubles
  double* racc = gacc + 24;               // 48
  double* qgs  = racc + 48;               // 512
  double* kgs  = qgs + 512;               // 512  (zone0 total < 16384)
  float* fvA = (float*)(wsb + 16384);     // 8 MB; reused as ohh/ohl after k_vT
  unsigned short* ohh = (unsigned short*)fvA;                   // 4 MB
  unsigned short* ohl = ohh + (size_t)NQB*NTOK*NH*DH;           // 4 MB
  float* mu_rstd = fvA + (size_t)NPAIR*NTOK*DH;   // 24576
  float* nuA  = mu_rstd + 24576;          // 2048
  float* Sarr = nuA + 2048;               // 64 (padded)
  float* inv_na_q = Sarr + 64;
  float* muqA     = inv_na_q + NROWS;
  float* tqA      = muqA + NROWS;
  float* inv_na_k = tqA + NROWS;
  float* skA      = inv_na_k + NROWS;
  float* rs_cos   = skA + NROWS;
  float* rs_cov   = rs_cos + NROWS;
  float* rs_marg  = rs_cov + NROWS;
  float* var_row  = rs_marg + NROWS;
  float* mxcos    = var_row + NROWS;
  float* mncos    = mxcos + NROWS;
  float* mxcov    = mncos + NROWS;
  float* mncov    = mxcov + NROWS;
  float* wp_out   = mncov + NROWS;        // 32 (padded)
  float* coef     = wp_out + 32;          // 32 (padded)
  float* endf     = coef + 32;
  size_t off16 = (size_t)((char*)endf - wsb);
  off16 = (off16 + 63) & ~(size_t)63;
  unsigned short* fqh  = (unsigned short*)(wsb + off16);
  unsigned short* fql  = fqh  + (size_t)NPAIR*NTOK*DH;
  unsigned short* fkh  = fql  + (size_t)NPAIR*NTOK*DH;
  unsigned short* fkl  = fkh  + (size_t)NPAIR*NTOK*DH;
  unsigned short* fvTh = fkl  + (size_t)NPAIR*NTOK*DH;
  unsigned short* fvTl = fvTh + (size_t)NPAIR*NTOK*DH;
  unsigned short* Wth  = fvTl + (size_t)NPAIR*NTOK*DH;
  unsigned short* Wtl  = Wth  + (size_t)DIMX*DIMX;
  unsigned short* Woth = Wtl  + (size_t)DIMX*DIMX;
  unsigned short* Wotl = Woth + (size_t)DIMX*DIMX;
  size_t need = (size_t)((char*)(Wotl + (size_t)DIMX*DIMX) - wsb);
  if (ws_size < need) return;  // fail cleanly rather than corrupt

  hipMemsetAsync(wsb, 0, 16384, stream);
  k_lnstats<<<3072, 256, 0, stream>>>(q, k, v, mu_rstd);
  k_splitW<<<dim3(8,8,2), 256, 0, stream>>>(W_in, W_out, Wth, Wtl, Woth, Wotl);
  k_projmm<<<dim3(64,4,3), 256, 0, stream>>>(q, k, v, ln_g, ln_b, Wth, Wtl,
                                             mu_rstd, fqh, fql, fkh, fkl, fvA,
                                             qgs, kgs);
  k_vT<<<dim3(16,32), 256, 0, stream>>>(fvA, fvTh, fvTl);
  k_nu<<<32, 256, 0, stream>>>(fkh, fkl, nuA, Sarr);
  k_rows<<<8192, 256, 0, stream>>>(fqh, fql, fkh, fkl, nuA,
                                   inv_na_q, muqA, tqA, inv_na_k, skA);
  k_wp<<<1, 256, 0, stream>>>(qgs, kgs, wp_W1, wp_b1, wp_lg, wp_lb,
                              wp_W2, wp_b2, wp_W3, wp_b3, wtemp, wp_out);
  k_passA<<<1024, 256, 0, stream>>>(fqh, fql, fkh, fkl,
                                    inv_na_q, muqA, tqA, inv_na_k, skA, Sarr,
                                    rs_cos, rs_cov, rs_marg,
                                    mxcos, mncos, mxcov, mncov, gacc);
  k_rowfin<<<128, 256, 0, stream>>>(rs_cos, rs_cov, rs_marg, var_row, racc);
  k_final<<<1, 64, 0, stream>>>(gacc, racc, wp_out, coef);
  k_pv<<<1024, 256, 0, stream>>>(fqh, fql, fkh, fkl, fvTh, fvTl,
                                 inv_na_q, muqA, tqA, inv_na_k, skA, Sarr,
                                 var_row, mxcos, mncos, mxcov, mncov, coef,
                                 ohh, ohl);
  k_outmm<<<dim3(64,4), 256, 0, stream>>>(ohh, ohl, Woth, Wotl, b_out, out);
}